// Round 13
// baseline (3215.548 us; speedup 1.0000x reference)
//
#include <hip/hip_runtime.h>

// ---------------------------------------------------------------------------
// GCNnet: 3x GCNConv (40->40->80->128) + global max pool + MLP(128->512->2) + softmax
// N=100000 nodes, E=1600000 edges, G=512 graphs.
// Round 21 (= R20 resubmit; prior bench was an infra failure, not a kernel
// fault). R17/R18/R19 all land at ~102us for conv3 -> the barrier between
// the degree-skewed gather phase and the gemm phase convoys waves (occupancy
// 33% regardless of block geometry; standalone barrier-free gather = 70%).
// Fix: BARRIER-FREE fusion. thread = (node, 32-col slice), TPN=4; each thread
// gathers agg into REGISTERS (4x redundant, ~6us chip) and runs its own
// 32-col gemm slice immediately. K split in 2 halves of 40 to cap VGPR
// (ag 10xfloat4/pass + acc 8xfloat4 persistent). 4 lanes/node broadcast-load
// the same H bytes; W wave-loads merge to one 512B line. Only barrier left
// is the tiny pool flush.
// ---------------------------------------------------------------------------

static inline int cdiv(long a, int b) { return (int)((a + b - 1) / b); }
static inline size_t align256(size_t x) { return (x + 255) & ~(size_t)255; }

#define FXSCALE 16777216.0f           // 2^24
#define SCHUNK  1024                  // elements per scan block
#define BKT_SHIFT 6                   // 64 nodes per bucket
#define MAXNB   2048                  // LDS histogram capacity (N <= 131072)
#define TB      256                   // histogram tiles

__device__ __forceinline__ float bf2f(unsigned short u) {
    return __uint_as_float(((unsigned int)u) << 16);
}
__device__ __forceinline__ unsigned short f2bf(float f) {   // round-nearest-even
    unsigned int u = __float_as_uint(f);
    return (unsigned short)((u + 0x7FFFu + ((u >> 16) & 1u)) >> 16);
}

#define ACC4(A, U, M)                                                         \
    do {                                                                      \
        A.x += bf2f((U).x) * (M); A.y += bf2f((U).y) * (M);                   \
        A.z += bf2f((U).z) * (M); A.w += bf2f((U).w) * (M);                   \
    } while (0)

// Pass A: per-tile LDS histogram over NB buckets (bucket = col>>6).
// gHist[tile][bucket]. Fused: x f32 -> bf16 (unpadded rows, stride 40).
__global__ __launch_bounds__(512)
void histA_kernel(const int* __restrict__ col, unsigned int* __restrict__ gHist,
                  int E, int NB, int chunk,
                  const float* __restrict__ x, ushort* __restrict__ xbf, long n4) {
    __shared__ unsigned int hist[MAXNB];
    int t = blockIdx.x;
    for (int i = threadIdx.x; i < NB; i += 512) hist[i] = 0u;
    __syncthreads();
    int s = t * chunk, e = min(s + chunk, E);
    for (int i = s + threadIdx.x; i < e; i += 512)
        atomicAdd(&hist[(unsigned int)col[i] >> BKT_SHIFT], 1u);
    // fused f2bf: i/10 = row, i%10 = float4 slot -> xbf[row*40 + slot*4]
    long gid = (long)t * 512 + threadIdx.x, gstride = (long)TB * 512;
    for (long i = gid; i < n4; i += gstride) {
        float4 v = ((const float4*)x)[i];
        long r = i / 10, c = i % 10;
        *(ushort4*)(xbf + r * 40 + c * 4) =
            make_ushort4(f2bf(v.x), f2bf(v.y), f2bf(v.z), f2bf(v.w));
    }
    __syncthreads();
    for (int b = threadIdx.x; b < NB; b += 512)
        gHist[(size_t)t * NB + b] = hist[b];
}

// scan phase A (histogram variant): per-block sums of the bucket-major view
// element i -> gHist[(i&255)*NB + (i>>8)]   (i = bucket*256 + tile)
__global__ void scanAH_kernel(const unsigned int* __restrict__ gHist,
                              int* __restrict__ blockSums, int TOT, int NB) {
    __shared__ int wred[4];
    int tid = threadIdx.x, lane = tid & 63, wid = tid >> 6;
    int i0 = blockIdx.x * SCHUNK + tid * 4;
    int s = 0;
#pragma unroll
    for (int k = 0; k < 4; ++k) {
        int i = i0 + k;
        if (i < TOT) s += (int)gHist[(size_t)(i & 255) * NB + (i >> 8)];
    }
#pragma unroll
    for (int off = 32; off > 0; off >>= 1) s += __shfl_down(s, off, 64);
    if (lane == 0) wred[wid] = s;
    __syncthreads();
    if (tid == 0) blockSums[blockIdx.x] = wred[0] + wred[1] + wred[2] + wred[3];
}

// scan phase B: one block, exclusive scan of blockSums[nb] (nb <= 1024);
// writes grand total into offs[N] (= E).
__global__ void scanB_kernel(int* __restrict__ blockSums, int* __restrict__ offs,
                             int nb, int N) {
    __shared__ int wsum[16];
    int tid = threadIdx.x, lane = tid & 63, wid = tid >> 6;
    int v = (tid < nb) ? blockSums[tid] : 0;
    int incl = v;
#pragma unroll
    for (int off = 1; off < 64; off <<= 1) {
        int t = __shfl_up(incl, off, 64);
        if (lane >= off) incl += t;
    }
    if (lane == 63) wsum[wid] = incl;
    __syncthreads();
    if (wid == 0 && lane < 16) {
        int w = wsum[lane];
        int ic = w;
#pragma unroll
        for (int off = 1; off < 16; off <<= 1) {
            int t = __shfl_up(ic, off, 64);
            if (lane >= off) ic += t;
        }
        wsum[lane] = ic - w;   // exclusive
    }
    __syncthreads();
    if (tid < nb) blockSums[tid] = wsum[wid] + incl - v;   // exclusive prefix
    if (tid == 1023) offs[N] = wsum[15] + incl;            // grand total
}

// scan phase C (histogram variant): local exclusive scan + block offset ->
// scanned[i] = global output cursor for (bucket = i>>8, tile = i&255)
__global__ void scanCH_kernel(const unsigned int* __restrict__ gHist,
                              const int* __restrict__ blockSums,
                              unsigned int* __restrict__ scanned, int TOT, int NB) {
    __shared__ int wsum[4];
    int tid = threadIdx.x, lane = tid & 63, wid = tid >> 6;
    int i0 = blockIdx.x * SCHUNK + tid * 4;
    int v0 = 0, v1 = 0, v2 = 0, v3 = 0;
    if (i0 + 0 < TOT) v0 = (int)gHist[(size_t)((i0 + 0) & 255) * NB + ((i0 + 0) >> 8)];
    if (i0 + 1 < TOT) v1 = (int)gHist[(size_t)((i0 + 1) & 255) * NB + ((i0 + 1) >> 8)];
    if (i0 + 2 < TOT) v2 = (int)gHist[(size_t)((i0 + 2) & 255) * NB + ((i0 + 2) >> 8)];
    if (i0 + 3 < TOT) v3 = (int)gHist[(size_t)((i0 + 3) & 255) * NB + ((i0 + 3) >> 8)];
    int sum = v0 + v1 + v2 + v3;
    int incl = sum;
#pragma unroll
    for (int off = 1; off < 64; off <<= 1) {
        int t = __shfl_up(incl, off, 64);
        if (lane >= off) incl += t;
    }
    if (lane == 63) wsum[wid] = incl;
    __syncthreads();
    if (tid == 0) {
        int c = 0;
#pragma unroll
        for (int k = 0; k < 4; ++k) { int t = wsum[k]; wsum[k] = c; c += t; }
    }
    __syncthreads();
    int pre = blockSums[blockIdx.x] + wsum[wid] + (incl - sum);
    if (i0 + 0 < TOT) scanned[i0 + 0] = (unsigned int)pre;
    if (i0 + 1 < TOT) scanned[i0 + 1] = (unsigned int)(pre + v0);
    if (i0 + 2 < TOT) scanned[i0 + 2] = (unsigned int)(pre + v0 + v1);
    if (i0 + 3 < TOT) scanned[i0 + 3] = (unsigned int)(pre + v0 + v1 + v2);
}

// Pass C: scatter edges into bucket-grouped semi[] via LDS cursors.
// semi[pos] = {row | (col&63)<<17, wbits} (int2, row < 2^17).
__global__ __launch_bounds__(512)
void scatterC_kernel(const int* __restrict__ row, const int* __restrict__ col,
                     const float* __restrict__ w,
                     const unsigned int* __restrict__ scanned,
                     int2* __restrict__ semi, int E, int NB, int chunk) {
    __shared__ unsigned int cur[MAXNB];
    int t = blockIdx.x;
    for (int b = threadIdx.x; b < NB; b += 512)
        cur[b] = scanned[(size_t)b * TB + t];
    __syncthreads();
    int s = t * chunk, e = min(s + chunk, E);
    for (int i = s + threadIdx.x; i < e; i += 512) {
        int c = col[i];
        unsigned int pos = atomicAdd(&cur[(unsigned int)c >> BKT_SHIFT], 1u);
        semi[pos] = make_int2(row[i] | ((c & 63) << 17), __float_as_int(w[i]));
    }
}

// Pass D: one block per bucket (64 nodes). Fine counting sort by c6,
// per-node weighted degree (fixed-point LDS atomics) -> perm {row,wbits},
// offs, dinv. All atomics LDS.
__global__ __launch_bounds__(256)
void fineD_kernel(const int2* __restrict__ semi, const unsigned int* __restrict__ scanned,
                  int* __restrict__ offs, float* __restrict__ dinv,
                  int2* __restrict__ perm, int E, int N, int NB) {
    __shared__ unsigned int cnt[64], cur[64], wsum[64];
    __shared__ int nodeOffs[64];
    int b = blockIdx.x, tid = threadIdx.x;
    int s = (int)scanned[(size_t)b * TB];
    int e = (b + 1 < NB) ? (int)scanned[(size_t)(b + 1) * TB] : E;
    if (tid < 64) { cnt[tid] = 0u; wsum[tid] = 0u; }
    __syncthreads();
    for (int i = s + tid; i < e; i += 256) {
        int2 v = semi[i];
        int c6 = (v.x >> 17) & 63;
        atomicAdd(&cnt[c6], 1u);
        atomicAdd(&wsum[c6], (unsigned int)llrintf(__int_as_float(v.y) * FXSCALE));
    }
    __syncthreads();
    if (tid < 64) {
        int v = (int)cnt[tid];
        int incl = v;
#pragma unroll
        for (int off = 1; off < 64; off <<= 1) {
            int u = __shfl_up(incl, off, 64);
            if (tid >= off) incl += u;
        }
        nodeOffs[tid] = incl - v;          // exclusive within bucket
        cur[tid] = (unsigned int)(incl - v);
    }
    __syncthreads();
    for (int i = s + tid; i < e; i += 256) {
        int2 v = semi[i];
        int c6 = (v.x >> 17) & 63;
        unsigned int r = atomicAdd(&cur[c6], 1u);
        perm[s + (int)r] = make_int2(v.x & 0x1FFFF, v.y);   // {row, wbits}
    }
    if (tid < 64) {
        int node = (b << BKT_SHIFT) + tid;
        if (node < N) {
            offs[node] = s + nodeOffs[tid];
            float deg = (float)wsum[tid] * (1.0f / FXSCALE);
            dinv[node] = rsqrtf(deg + 1.0f);
        }
    }
    if (b == NB - 1 && tid == 0) offs[N] = E;
}

// Pass E: perm.y = dinv[row] * w * dinv[col]  (thread per destination node)
__global__ void normE_kernel(const int* __restrict__ offs, const float* __restrict__ dinv,
                             int2* __restrict__ perm, int N) {
    int n = blockIdx.x * blockDim.x + threadIdx.x;
    if (n >= N) return;
    int s = offs[n], e = offs[n + 1];
    float dc = dinv[n];
    for (int j = s; j < e; ++j) {
        int2 p = perm[j];
        float nm = dinv[p.x] * __int_as_float(p.y) * dc;
        perm[j] = make_int2(p.x, __float_as_int(nm));
    }
}

// Fused conv (conv1/conv2): phase1 = R11 gather into LDS agg (rows padded to
// K+4 floats vs phase-2 bank conflicts); sync; phase2 = gemm from LDS, relu,
// bf16 out. Removes the bufA global round-trip entirely.
template<int K, int FOUT, int NPB, int BLK>
__global__ __launch_bounds__(BLK)
void fused_conv_kernel(const int* __restrict__ offs, const int2* __restrict__ perm,
                       const ushort* __restrict__ H, const float* __restrict__ dinv,
                       const float* __restrict__ W, const float* __restrict__ bias,
                       ushort* __restrict__ out, int N) {
    constexpr int TPN = K / 4;
    constexpr int TPQ = FOUT / 4;
    constexpr int NPT = 4;
    constexpr int KP = K + 4;              // padded agg row (floats)
    static_assert((NPB * TPN) % BLK == 0, "phase1 tiling");
    static_assert((NPB / NPT) * TPQ == BLK, "phase2 tiling");
    __shared__ float wsm[K * FOUT];
    __shared__ float aggs[NPB * KP];
    for (int i = threadIdx.x; i < K * FOUT; i += BLK) wsm[i] = W[i];

    // ---- phase 1: gather into LDS ----
#pragma unroll
    for (int p0 = 0; p0 < NPB * TPN; p0 += BLK) {
        int p = p0 + threadIdx.x;
        int nl = p / TPN, q = p % TPN;
        int node = blockIdx.x * NPB + nl;
        float4 a0 = make_float4(0.f, 0.f, 0.f, 0.f);
        float4 a1 = make_float4(0.f, 0.f, 0.f, 0.f);
        if (node < N) {
            int s = offs[node], e = offs[node + 1];
            int j = s;
            for (; j + 4 <= e; j += 4) {
                int2 p0e = perm[j + 0], p1e = perm[j + 1];
                int2 p2e = perm[j + 2], p3e = perm[j + 3];
                ushort4 u0 = *(const ushort4*)(H + (long)p0e.x * K + q * 4);
                ushort4 u1 = *(const ushort4*)(H + (long)p1e.x * K + q * 4);
                ushort4 u2 = *(const ushort4*)(H + (long)p2e.x * K + q * 4);
                ushort4 u3 = *(const ushort4*)(H + (long)p3e.x * K + q * 4);
                ACC4(a0, u0, __int_as_float(p0e.y));
                ACC4(a1, u1, __int_as_float(p1e.y));
                ACC4(a0, u2, __int_as_float(p2e.y));
                ACC4(a1, u3, __int_as_float(p3e.y));
            }
            for (; j < e; ++j) {
                int2 pe = perm[j];
                ushort4 u = *(const ushort4*)(H + (long)pe.x * K + q * 4);
                ACC4(a0, u, __int_as_float(pe.y));
            }
            float di = dinv[node], d2 = di * di;
            ushort4 su = *(const ushort4*)(H + (long)node * K + q * 4);
            ACC4(a0, su, d2);
        }
        a0.x += a1.x; a0.y += a1.y; a0.z += a1.z; a0.w += a1.w;
        *(float4*)&aggs[nl * KP + q * 4] = a0;
    }
    __syncthreads();

    // ---- phase 2: gemm from LDS ----
    int q = threadIdx.x % TPQ, pg = threadIdx.x / TPQ;
    long nbase = (long)blockIdx.x * NPB + (long)pg * NPT;
    float4 acc[NPT];
#pragma unroll
    for (int t = 0; t < NPT; ++t) acc[t] = make_float4(0.f, 0.f, 0.f, 0.f);
    const float* wq = wsm + q * 4;
#pragma unroll 4
    for (int i = 0; i < K / 4; ++i) {
        float4 xv[NPT];
#pragma unroll
        for (int t = 0; t < NPT; ++t)
            xv[t] = *(const float4*)&aggs[(pg * NPT + t) * KP + i * 4];
#pragma unroll
        for (int j = 0; j < 4; ++j) {
            float4 wv = *(const float4*)(wq + (i * 4 + j) * FOUT);
#pragma unroll
            for (int t = 0; t < NPT; ++t) {
                float v = ((const float*)&xv[t])[j];
                acc[t].x += v * wv.x; acc[t].y += v * wv.y;
                acc[t].z += v * wv.z; acc[t].w += v * wv.w;
            }
        }
    }
    float4 bv = *(const float4*)(bias + q * 4);
#pragma unroll
    for (int t = 0; t < NPT; ++t) {
        long n = nbase + t;
        if (n < N) {
            float ox = fmaxf(acc[t].x + bv.x, 0.f);
            float oy = fmaxf(acc[t].y + bv.y, 0.f);
            float oz = fmaxf(acc[t].z + bv.z, 0.f);
            float ow = fmaxf(acc[t].w + bv.w, 0.f);
            *(ushort4*)(out + n * FOUT + q * 4) =
                make_ushort4(f2bf(ox), f2bf(oy), f2bf(oz), f2bf(ow));
        }
    }
}

// conv3 barrier-free direct: thread = (node, 32-col slice), TPN=4.
// Each thread gathers agg into REGISTERS (4x redundant across the col
// slices) in two K-halves (ag = 10 float4/pass) and immediately accumulates
// its 32-col gemm slice (acc = 8 float4, persists across halves).
// 4 lanes of a node broadcast-load identical H bytes (merged); the wave's
// W loads cover one contiguous 512B row. No gather/gemm barrier -> no
// degree-straggler convoy; waves drift freely between memory and FMA.
template<int BLK>   // 256
__global__ __launch_bounds__(BLK)
void conv3_direct_kernel(const int* __restrict__ offs, const int2* __restrict__ perm,
                         const ushort* __restrict__ H, const float* __restrict__ dinv,
                         const float* __restrict__ W, const float* __restrict__ bias,
                         const int* __restrict__ batch,
                         unsigned int* __restrict__ g, int N) {
    constexpr int FOUT = 128;
    constexpr int TPN = 4;               // threads per node (32 cols each)
    constexpr int NPB = BLK / TPN;       // 64 nodes per block
    __shared__ unsigned int gma[2 * FOUT];
    __shared__ int gfirst;
    int bb = blockIdx.x * NPB;
    if (threadIdx.x == 0) gfirst = batch[min(bb, N - 1)];
    for (int i = threadIdx.x; i < 2 * FOUT; i += BLK) gma[i] = 0u;
    __syncthreads();                      // gma init before any pool atomics

    int cg = threadIdx.x & 3, nl = threadIdx.x >> 2;
    int node = bb + nl;
    bool valid = node < N;
    int s = 0, e = 0;
    float d2 = 0.f;
    if (valid) {
        s = offs[node]; e = offs[node + 1];
        float di = dinv[node]; d2 = di * di;
    }

    float4 acc[8];
#pragma unroll
    for (int i = 0; i < 8; ++i) acc[i] = make_float4(0.f, 0.f, 0.f, 0.f);

#pragma unroll
    for (int half = 0; half < 2; ++half) {
        float4 ag[10];
#pragma unroll
        for (int i = 0; i < 10; ++i) ag[i] = make_float4(0.f, 0.f, 0.f, 0.f);
        const ushort* Hh = H + half * 40;
        for (int j = s; j < e; ++j) {
            int2 p = perm[j];                        // broadcast across 4 lanes
            float m = __int_as_float(p.y);
            const ushort* hb = Hh + (long)p.x * 80;
#pragma unroll
            for (int kk = 0; kk < 10; ++kk) {
                ushort4 u = *(const ushort4*)(hb + kk * 4);
                ACC4(ag[kk], u, m);
            }
        }
        if (valid) {                                  // self-loop term
            const ushort* hb = Hh + (long)node * 80;
#pragma unroll
            for (int kk = 0; kk < 10; ++kk) {
                ushort4 u = *(const ushort4*)(hb + kk * 4);
                ACC4(ag[kk], u, d2);
            }
        }
        // partial gemm for this K-half: k = half*40 + kk*4 + c
        const float* Wc = W + cg * 32;
#pragma unroll
        for (int kk = 0; kk < 10; ++kk) {
#pragma unroll
            for (int c = 0; c < 4; ++c) {
                float kv = (c == 0) ? ag[kk].x : (c == 1) ? ag[kk].y
                          : (c == 2) ? ag[kk].z : ag[kk].w;
                const float* wr = Wc + (half * 40 + kk * 4 + c) * FOUT;
#pragma unroll
                for (int q8 = 0; q8 < 8; ++q8) {
                    float4 wv = *(const float4*)(wr + q8 * 4);
                    acc[q8].x += kv * wv.x; acc[q8].y += kv * wv.y;
                    acc[q8].z += kv * wv.z; acc[q8].w += kv * wv.w;
                }
            }
        }
    }

    // bias + relu + hierarchical pool
    if (valid) {
        int bn = batch[node];
        int rel = bn - gfirst;
#pragma unroll
        for (int q8 = 0; q8 < 8; ++q8) {
            int col = cg * 32 + q8 * 4;
            float4 bv = *(const float4*)(bias + col);
            unsigned int bx = __float_as_uint(fmaxf(acc[q8].x + bv.x, 0.f));
            unsigned int by = __float_as_uint(fmaxf(acc[q8].y + bv.y, 0.f));
            unsigned int bz = __float_as_uint(fmaxf(acc[q8].z + bv.z, 0.f));
            unsigned int bw = __float_as_uint(fmaxf(acc[q8].w + bv.w, 0.f));
            if (rel < 2) {
                unsigned int* d = gma + rel * FOUT + col;
                atomicMax(d + 0, bx); atomicMax(d + 1, by);
                atomicMax(d + 2, bz); atomicMax(d + 3, bw);
            } else {
                unsigned int* d = g + (long)bn * FOUT + col;
                atomicMax(d + 0, bx); atomicMax(d + 1, by);
                atomicMax(d + 2, bz); atomicMax(d + 3, bw);
            }
        }
    }
    __syncthreads();
    for (int i = threadIdx.x; i < 2 * FOUT; i += BLK) {
        unsigned int v = gma[i];
        if (v) atomicMax(&g[(long)(gfirst + i / FOUT) * FOUT + (i % FOUT)], v);
    }
}

// one block per graph: relu(g@Wfc1+bfc1) @ Wfc2 + bfc2 -> softmax
__global__ void fc_kernel(const float* __restrict__ g, const float* __restrict__ Wfc1,
                          const float* __restrict__ bfc1, const float* __restrict__ Wfc2,
                          const float* __restrict__ bfc2, float* __restrict__ out) {
    __shared__ float gs[128];
    __shared__ float red0[256], red1[256];
    int b = blockIdx.x, tid = threadIdx.x;
    if (tid < 128) gs[tid] = g[b * 128 + tid];
    __syncthreads();
    float h0 = bfc1[tid], h1 = bfc1[tid + 256];
    for (int k = 0; k < 128; ++k) {
        float gv = gs[k];
        h0 += gv * Wfc1[k * 512 + tid];
        h1 += gv * Wfc1[k * 512 + tid + 256];
    }
    h0 = fmaxf(h0, 0.f); h1 = fmaxf(h1, 0.f);
    red0[tid] = h0 * Wfc2[tid * 2 + 0] + h1 * Wfc2[(tid + 256) * 2 + 0];
    red1[tid] = h0 * Wfc2[tid * 2 + 1] + h1 * Wfc2[(tid + 256) * 2 + 1];
    __syncthreads();
    for (int s = 128; s > 0; s >>= 1) {
        if (tid < s) { red0[tid] += red0[tid + s]; red1[tid] += red1[tid + s]; }
        __syncthreads();
    }
    if (tid == 0) {
        float L0 = red0[0] + bfc2[0], L1 = red1[0] + bfc2[1];
        float m = fmaxf(L0, L1);
        float e0 = expf(L0 - m), e1 = expf(L1 - m);
        float inv = 1.f / (e0 + e1);
        out[b * 2 + 0] = e0 * inv;
        out[b * 2 + 1] = e1 * inv;
    }
}

extern "C" void kernel_launch(void* const* d_in, const int* in_sizes, int n_in,
                              void* d_out, int out_size, void* d_ws, size_t ws_size,
                              hipStream_t stream) {
    const float* x     = (const float*)d_in[0];
    const int*   ei    = (const int*)d_in[1];
    const float* ew    = (const float*)d_in[2];
    const int*   batch = (const int*)d_in[3];
    const float* W1    = (const float*)d_in[4];
    const float* b1    = (const float*)d_in[5];
    const float* W2    = (const float*)d_in[6];
    const float* b2    = (const float*)d_in[7];
    const float* W3    = (const float*)d_in[8];
    const float* b3    = (const float*)d_in[9];
    const float* Wfc1  = (const float*)d_in[10];
    const float* bfc1  = (const float*)d_in[11];
    const float* Wfc2  = (const float*)d_in[12];
    const float* bfc2  = (const float*)d_in[13];

    const int N = in_sizes[3];      // 100000
    const int E = in_sizes[2];      // 1600000
    const int* row = ei;
    const int* col = ei + E;

    char* ws = (char*)d_ws;
    float* dinv   = (float*)ws;              ws += align256((size_t)N * 4);
    int*   offs   = (int*)ws;                ws += align256((size_t)(N + 1) * 4);
    int*   bsums  = (int*)ws;                ws += align256((size_t)1024 * 4);
    int2*  perm   = (int2*)ws;               ws += align256((size_t)E * 8);
    float* bufA   = (float*)ws;              ws += align256((size_t)N * 128 * 4);  // build transients
    ushort* bufH1 = (ushort*)ws;             ws += align256((size_t)N * 40 * 2);   // H1 bf16
    ushort* bufH2 = (ushort*)ws;             ws += align256((size_t)N * 80 * 2);   // H2 bf16
    ushort* xbf   = (ushort*)ws;             ws += align256((size_t)N * 40 * 2);   // x bf16
    float* g      = (float*)ws;              ws += align256((size_t)512 * 128 * 4);

    const int NB   = cdiv(N, 64);            // 1563 buckets (<= MAXNB)
    const int TOT  = NB * TB;                // (bucket, tile) cells = 400128
    const int chunkE = cdiv(E, TB);          // edges per tile = 6250
    const int nScanH = cdiv(TOT, SCHUNK);    // 391 (<= 1024)

    // transients aliased into bufA (51.2MB; all dead before convs):
    // semi int2 (12.8MB) | gHist u32[TOT] (1.6MB) | scanned u32[TOT] (1.6MB)
    int2* semi = (int2*)bufA;
    unsigned int* gHist =
        (unsigned int*)((char*)bufA + align256((size_t)E * 8));
    unsigned int* scanned =
        (unsigned int*)((char*)gHist + align256((size_t)TOT * 4));

    const int B = 256;

    // --- atomic-free CSR build ---
    histA_kernel<<<TB, 512, 0, stream>>>(col, gHist, E, NB, chunkE,
                                         x, xbf, (long)N * 10);
    scanAH_kernel<<<nScanH, B, 0, stream>>>(gHist, bsums, TOT, NB);
    scanB_kernel<<<1, 1024, 0, stream>>>(bsums, offs, nScanH, N);
    scanCH_kernel<<<nScanH, B, 0, stream>>>(gHist, bsums, scanned, TOT, NB);
    scatterC_kernel<<<TB, 512, 0, stream>>>(row, col, ew, scanned, semi, E, NB, chunkE);
    fineD_kernel<<<NB, 256, 0, stream>>>(semi, scanned, offs, dinv, perm, E, N, NB);
    normE_kernel<<<cdiv(N, B), B, 0, stream>>>(offs, dinv, perm, N);

    // --- conv1 fused: H1 = relu((A*x)@W1 + b1) -> bufH1 (bf16) ---
    fused_conv_kernel<40, 40, 128, 320><<<cdiv(N, 128), 320, 0, stream>>>(
        offs, perm, xbf, dinv, W1, b1, bufH1, N);

    // --- conv2 fused: H2 = relu((A*H1)@W2 + b2) -> bufH2 (bf16) ---
    fused_conv_kernel<40, 80, 64, 320><<<cdiv(N, 64), 320, 0, stream>>>(
        offs, perm, bufH1, dinv, W2, b2, bufH2, N);

    // --- conv3 barrier-free direct: pool(relu((A*H2)@W3 + b3)) -> g ---
    hipMemsetAsync(g, 0, (size_t)512 * 128 * 4, stream);
    conv3_direct_kernel<256><<<cdiv(N, 64), 256, 0, stream>>>(
        offs, perm, bufH2, dinv, W3, b3, batch, (unsigned int*)g, N);

    // --- MLP + softmax ---
    fc_kernel<<<512, 256, 0, stream>>>(g, Wfc1, bfc1, Wfc2, bfc2, (float*)d_out);
}

// Round 14
// 368.800 us; speedup vs baseline: 8.7189x; 8.7189x over previous
//
#include <hip/hip_runtime.h>

// ---------------------------------------------------------------------------
// GCNnet: 3x GCNConv (40->40->80->128) + global max pool + MLP(128->512->2) + softmax
// N=100000 nodes, E=1600000 edges, G=512 graphs.
// Round 22: REVERT to R17 (measured best, 365.4us). R20's barrier-free conv3
// hit the 256-VGPR cap and spilled accumulators to scratch (WRITE_SIZE 2.9GB,
// 2945us). conv3 ledger: split=103, fused-2phase=101.6 (BEST), chunk-pipe=227,
// small-block=102.6, reg-direct=2945 -> R17's two-phase fused kernel is the
// plateau for this structure; pinning it.
// Pipeline: atomic-free counting-sort CSR build -> fused gather+gemm conv1/2
// (LDS hand-off, bf16 H) -> fused conv3 (gather->LDS, gemm W3-from-global,
// hierarchical max-pool) -> fc+softmax.
// ---------------------------------------------------------------------------

static inline int cdiv(long a, int b) { return (int)((a + b - 1) / b); }
static inline size_t align256(size_t x) { return (x + 255) & ~(size_t)255; }

#define FXSCALE 16777216.0f           // 2^24
#define SCHUNK  1024                  // elements per scan block
#define BKT_SHIFT 6                   // 64 nodes per bucket
#define MAXNB   2048                  // LDS histogram capacity (N <= 131072)
#define TB      256                   // histogram tiles

__device__ __forceinline__ float bf2f(unsigned short u) {
    return __uint_as_float(((unsigned int)u) << 16);
}
__device__ __forceinline__ unsigned short f2bf(float f) {   // round-nearest-even
    unsigned int u = __float_as_uint(f);
    return (unsigned short)((u + 0x7FFFu + ((u >> 16) & 1u)) >> 16);
}

#define ACC4(A, U, M)                                                         \
    do {                                                                      \
        A.x += bf2f((U).x) * (M); A.y += bf2f((U).y) * (M);                   \
        A.z += bf2f((U).z) * (M); A.w += bf2f((U).w) * (M);                   \
    } while (0)

// Pass A: per-tile LDS histogram over NB buckets (bucket = col>>6).
// gHist[tile][bucket]. Fused: x f32 -> bf16 (unpadded rows, stride 40).
__global__ __launch_bounds__(512)
void histA_kernel(const int* __restrict__ col, unsigned int* __restrict__ gHist,
                  int E, int NB, int chunk,
                  const float* __restrict__ x, ushort* __restrict__ xbf, long n4) {
    __shared__ unsigned int hist[MAXNB];
    int t = blockIdx.x;
    for (int i = threadIdx.x; i < NB; i += 512) hist[i] = 0u;
    __syncthreads();
    int s = t * chunk, e = min(s + chunk, E);
    for (int i = s + threadIdx.x; i < e; i += 512)
        atomicAdd(&hist[(unsigned int)col[i] >> BKT_SHIFT], 1u);
    // fused f2bf: i/10 = row, i%10 = float4 slot -> xbf[row*40 + slot*4]
    long gid = (long)t * 512 + threadIdx.x, gstride = (long)TB * 512;
    for (long i = gid; i < n4; i += gstride) {
        float4 v = ((const float4*)x)[i];
        long r = i / 10, c = i % 10;
        *(ushort4*)(xbf + r * 40 + c * 4) =
            make_ushort4(f2bf(v.x), f2bf(v.y), f2bf(v.z), f2bf(v.w));
    }
    __syncthreads();
    for (int b = threadIdx.x; b < NB; b += 512)
        gHist[(size_t)t * NB + b] = hist[b];
}

// scan phase A (histogram variant): per-block sums of the bucket-major view
// element i -> gHist[(i&255)*NB + (i>>8)]   (i = bucket*256 + tile)
__global__ void scanAH_kernel(const unsigned int* __restrict__ gHist,
                              int* __restrict__ blockSums, int TOT, int NB) {
    __shared__ int wred[4];
    int tid = threadIdx.x, lane = tid & 63, wid = tid >> 6;
    int i0 = blockIdx.x * SCHUNK + tid * 4;
    int s = 0;
#pragma unroll
    for (int k = 0; k < 4; ++k) {
        int i = i0 + k;
        if (i < TOT) s += (int)gHist[(size_t)(i & 255) * NB + (i >> 8)];
    }
#pragma unroll
    for (int off = 32; off > 0; off >>= 1) s += __shfl_down(s, off, 64);
    if (lane == 0) wred[wid] = s;
    __syncthreads();
    if (tid == 0) blockSums[blockIdx.x] = wred[0] + wred[1] + wred[2] + wred[3];
}

// scan phase B: one block, exclusive scan of blockSums[nb] (nb <= 1024);
// writes grand total into offs[N] (= E).
__global__ void scanB_kernel(int* __restrict__ blockSums, int* __restrict__ offs,
                             int nb, int N) {
    __shared__ int wsum[16];
    int tid = threadIdx.x, lane = tid & 63, wid = tid >> 6;
    int v = (tid < nb) ? blockSums[tid] : 0;
    int incl = v;
#pragma unroll
    for (int off = 1; off < 64; off <<= 1) {
        int t = __shfl_up(incl, off, 64);
        if (lane >= off) incl += t;
    }
    if (lane == 63) wsum[wid] = incl;
    __syncthreads();
    if (wid == 0 && lane < 16) {
        int w = wsum[lane];
        int ic = w;
#pragma unroll
        for (int off = 1; off < 16; off <<= 1) {
            int t = __shfl_up(ic, off, 64);
            if (lane >= off) ic += t;
        }
        wsum[lane] = ic - w;   // exclusive
    }
    __syncthreads();
    if (tid < nb) blockSums[tid] = wsum[wid] + incl - v;   // exclusive prefix
    if (tid == 1023) offs[N] = wsum[15] + incl;            // grand total
}

// scan phase C (histogram variant): local exclusive scan + block offset ->
// scanned[i] = global output cursor for (bucket = i>>8, tile = i&255)
__global__ void scanCH_kernel(const unsigned int* __restrict__ gHist,
                              const int* __restrict__ blockSums,
                              unsigned int* __restrict__ scanned, int TOT, int NB) {
    __shared__ int wsum[4];
    int tid = threadIdx.x, lane = tid & 63, wid = tid >> 6;
    int i0 = blockIdx.x * SCHUNK + tid * 4;
    int v0 = 0, v1 = 0, v2 = 0, v3 = 0;
    if (i0 + 0 < TOT) v0 = (int)gHist[(size_t)((i0 + 0) & 255) * NB + ((i0 + 0) >> 8)];
    if (i0 + 1 < TOT) v1 = (int)gHist[(size_t)((i0 + 1) & 255) * NB + ((i0 + 1) >> 8)];
    if (i0 + 2 < TOT) v2 = (int)gHist[(size_t)((i0 + 2) & 255) * NB + ((i0 + 2) >> 8)];
    if (i0 + 3 < TOT) v3 = (int)gHist[(size_t)((i0 + 3) & 255) * NB + ((i0 + 3) >> 8)];
    int sum = v0 + v1 + v2 + v3;
    int incl = sum;
#pragma unroll
    for (int off = 1; off < 64; off <<= 1) {
        int t = __shfl_up(incl, off, 64);
        if (lane >= off) incl += t;
    }
    if (lane == 63) wsum[wid] = incl;
    __syncthreads();
    if (tid == 0) {
        int c = 0;
#pragma unroll
        for (int k = 0; k < 4; ++k) { int t = wsum[k]; wsum[k] = c; c += t; }
    }
    __syncthreads();
    int pre = blockSums[blockIdx.x] + wsum[wid] + (incl - sum);
    if (i0 + 0 < TOT) scanned[i0 + 0] = (unsigned int)pre;
    if (i0 + 1 < TOT) scanned[i0 + 1] = (unsigned int)(pre + v0);
    if (i0 + 2 < TOT) scanned[i0 + 2] = (unsigned int)(pre + v0 + v1);
    if (i0 + 3 < TOT) scanned[i0 + 3] = (unsigned int)(pre + v0 + v1 + v2);
}

// Pass C: scatter edges into bucket-grouped semi[] via LDS cursors.
// semi[pos] = {row | (col&63)<<17, wbits} (int2, row < 2^17).
__global__ __launch_bounds__(512)
void scatterC_kernel(const int* __restrict__ row, const int* __restrict__ col,
                     const float* __restrict__ w,
                     const unsigned int* __restrict__ scanned,
                     int2* __restrict__ semi, int E, int NB, int chunk) {
    __shared__ unsigned int cur[MAXNB];
    int t = blockIdx.x;
    for (int b = threadIdx.x; b < NB; b += 512)
        cur[b] = scanned[(size_t)b * TB + t];
    __syncthreads();
    int s = t * chunk, e = min(s + chunk, E);
    for (int i = s + threadIdx.x; i < e; i += 512) {
        int c = col[i];
        unsigned int pos = atomicAdd(&cur[(unsigned int)c >> BKT_SHIFT], 1u);
        semi[pos] = make_int2(row[i] | ((c & 63) << 17), __float_as_int(w[i]));
    }
}

// Pass D: one block per bucket (64 nodes). Fine counting sort by c6,
// per-node weighted degree (fixed-point LDS atomics) -> perm {row,wbits},
// offs, dinv. All atomics LDS.
__global__ __launch_bounds__(256)
void fineD_kernel(const int2* __restrict__ semi, const unsigned int* __restrict__ scanned,
                  int* __restrict__ offs, float* __restrict__ dinv,
                  int2* __restrict__ perm, int E, int N, int NB) {
    __shared__ unsigned int cnt[64], cur[64], wsum[64];
    __shared__ int nodeOffs[64];
    int b = blockIdx.x, tid = threadIdx.x;
    int s = (int)scanned[(size_t)b * TB];
    int e = (b + 1 < NB) ? (int)scanned[(size_t)(b + 1) * TB] : E;
    if (tid < 64) { cnt[tid] = 0u; wsum[tid] = 0u; }
    __syncthreads();
    for (int i = s + tid; i < e; i += 256) {
        int2 v = semi[i];
        int c6 = (v.x >> 17) & 63;
        atomicAdd(&cnt[c6], 1u);
        atomicAdd(&wsum[c6], (unsigned int)llrintf(__int_as_float(v.y) * FXSCALE));
    }
    __syncthreads();
    if (tid < 64) {
        int v = (int)cnt[tid];
        int incl = v;
#pragma unroll
        for (int off = 1; off < 64; off <<= 1) {
            int u = __shfl_up(incl, off, 64);
            if (tid >= off) incl += u;
        }
        nodeOffs[tid] = incl - v;          // exclusive within bucket
        cur[tid] = (unsigned int)(incl - v);
    }
    __syncthreads();
    for (int i = s + tid; i < e; i += 256) {
        int2 v = semi[i];
        int c6 = (v.x >> 17) & 63;
        unsigned int r = atomicAdd(&cur[c6], 1u);
        perm[s + (int)r] = make_int2(v.x & 0x1FFFF, v.y);   // {row, wbits}
    }
    if (tid < 64) {
        int node = (b << BKT_SHIFT) + tid;
        if (node < N) {
            offs[node] = s + nodeOffs[tid];
            float deg = (float)wsum[tid] * (1.0f / FXSCALE);
            dinv[node] = rsqrtf(deg + 1.0f);
        }
    }
    if (b == NB - 1 && tid == 0) offs[N] = E;
}

// Pass E: perm.y = dinv[row] * w * dinv[col]  (thread per destination node)
__global__ void normE_kernel(const int* __restrict__ offs, const float* __restrict__ dinv,
                             int2* __restrict__ perm, int N) {
    int n = blockIdx.x * blockDim.x + threadIdx.x;
    if (n >= N) return;
    int s = offs[n], e = offs[n + 1];
    float dc = dinv[n];
    for (int j = s; j < e; ++j) {
        int2 p = perm[j];
        float nm = dinv[p.x] * __int_as_float(p.y) * dc;
        perm[j] = make_int2(p.x, __float_as_int(nm));
    }
}

// Fused conv (conv1/conv2): phase1 = R11 gather into LDS agg (rows padded to
// K+4 floats vs phase-2 bank conflicts); sync; phase2 = gemm from LDS, relu,
// bf16 out. Removes the bufA global round-trip entirely.
template<int K, int FOUT, int NPB, int BLK>
__global__ __launch_bounds__(BLK)
void fused_conv_kernel(const int* __restrict__ offs, const int2* __restrict__ perm,
                       const ushort* __restrict__ H, const float* __restrict__ dinv,
                       const float* __restrict__ W, const float* __restrict__ bias,
                       ushort* __restrict__ out, int N) {
    constexpr int TPN = K / 4;
    constexpr int TPQ = FOUT / 4;
    constexpr int NPT = 4;
    constexpr int KP = K + 4;              // padded agg row (floats)
    static_assert((NPB * TPN) % BLK == 0, "phase1 tiling");
    static_assert((NPB / NPT) * TPQ == BLK, "phase2 tiling");
    __shared__ float wsm[K * FOUT];
    __shared__ float aggs[NPB * KP];
    for (int i = threadIdx.x; i < K * FOUT; i += BLK) wsm[i] = W[i];

    // ---- phase 1: gather into LDS ----
#pragma unroll
    for (int p0 = 0; p0 < NPB * TPN; p0 += BLK) {
        int p = p0 + threadIdx.x;
        int nl = p / TPN, q = p % TPN;
        int node = blockIdx.x * NPB + nl;
        float4 a0 = make_float4(0.f, 0.f, 0.f, 0.f);
        float4 a1 = make_float4(0.f, 0.f, 0.f, 0.f);
        if (node < N) {
            int s = offs[node], e = offs[node + 1];
            int j = s;
            for (; j + 4 <= e; j += 4) {
                int2 p0e = perm[j + 0], p1e = perm[j + 1];
                int2 p2e = perm[j + 2], p3e = perm[j + 3];
                ushort4 u0 = *(const ushort4*)(H + (long)p0e.x * K + q * 4);
                ushort4 u1 = *(const ushort4*)(H + (long)p1e.x * K + q * 4);
                ushort4 u2 = *(const ushort4*)(H + (long)p2e.x * K + q * 4);
                ushort4 u3 = *(const ushort4*)(H + (long)p3e.x * K + q * 4);
                ACC4(a0, u0, __int_as_float(p0e.y));
                ACC4(a1, u1, __int_as_float(p1e.y));
                ACC4(a0, u2, __int_as_float(p2e.y));
                ACC4(a1, u3, __int_as_float(p3e.y));
            }
            for (; j < e; ++j) {
                int2 pe = perm[j];
                ushort4 u = *(const ushort4*)(H + (long)pe.x * K + q * 4);
                ACC4(a0, u, __int_as_float(pe.y));
            }
            float di = dinv[node], d2 = di * di;
            ushort4 su = *(const ushort4*)(H + (long)node * K + q * 4);
            ACC4(a0, su, d2);
        }
        a0.x += a1.x; a0.y += a1.y; a0.z += a1.z; a0.w += a1.w;
        *(float4*)&aggs[nl * KP + q * 4] = a0;
    }
    __syncthreads();

    // ---- phase 2: gemm from LDS ----
    int q = threadIdx.x % TPQ, pg = threadIdx.x / TPQ;
    long nbase = (long)blockIdx.x * NPB + (long)pg * NPT;
    float4 acc[NPT];
#pragma unroll
    for (int t = 0; t < NPT; ++t) acc[t] = make_float4(0.f, 0.f, 0.f, 0.f);
    const float* wq = wsm + q * 4;
#pragma unroll 4
    for (int i = 0; i < K / 4; ++i) {
        float4 xv[NPT];
#pragma unroll
        for (int t = 0; t < NPT; ++t)
            xv[t] = *(const float4*)&aggs[(pg * NPT + t) * KP + i * 4];
#pragma unroll
        for (int j = 0; j < 4; ++j) {
            float4 wv = *(const float4*)(wq + (i * 4 + j) * FOUT);
#pragma unroll
            for (int t = 0; t < NPT; ++t) {
                float v = ((const float*)&xv[t])[j];
                acc[t].x += v * wv.x; acc[t].y += v * wv.y;
                acc[t].z += v * wv.z; acc[t].w += v * wv.w;
            }
        }
    }
    float4 bv = *(const float4*)(bias + q * 4);
#pragma unroll
    for (int t = 0; t < NPT; ++t) {
        long n = nbase + t;
        if (n < N) {
            float ox = fmaxf(acc[t].x + bv.x, 0.f);
            float oy = fmaxf(acc[t].y + bv.y, 0.f);
            float oz = fmaxf(acc[t].z + bv.z, 0.f);
            float ow = fmaxf(acc[t].w + bv.w, 0.f);
            *(ushort4*)(out + n * FOUT + q * 4) =
                make_ushort4(f2bf(ox), f2bf(oy), f2bf(oz), f2bf(ow));
        }
    }
}

// Fused conv3 + pool (R17, measured best): phase1 = gather NPB=64 nodes x 80
// feats into LDS (21.5KB); phase2 = 80->128 gemm with W3 from GLOBAL
// (coalesced, L1/L2-hot across all blocks) + relu + hierarchical max-pool.
// NPT=8, TPQ=32.
template<int K, int FOUT, int NPB, int BLK>
__global__ __launch_bounds__(BLK)
void fused_conv3_pool_kernel(const int* __restrict__ offs, const int2* __restrict__ perm,
                             const ushort* __restrict__ H, const float* __restrict__ dinv,
                             const float* __restrict__ W, const float* __restrict__ bias,
                             const int* __restrict__ batch,
                             unsigned int* __restrict__ g, int N) {
    constexpr int TPN = K / 4;             // 20
    constexpr int TPQ = FOUT / 4;          // 32
    constexpr int NPT = NPB / (BLK / TPQ); // 64 / 8 = 8
    constexpr int KP = K + 4;              // padded agg row (floats)
    static_assert((NPB * TPN) % BLK == 0, "phase1 tiling");
    static_assert((NPB / NPT) * TPQ == BLK, "phase2 tiling");
    __shared__ float aggs[NPB * KP];
    __shared__ unsigned int gma[2 * FOUT];
    __shared__ int gfirst;
    if (threadIdx.x == 0) gfirst = batch[min((int)(blockIdx.x * NPB), N - 1)];
    for (int i = threadIdx.x; i < 2 * FOUT; i += BLK) gma[i] = 0u;

    // ---- phase 1: gather into LDS ----
#pragma unroll
    for (int p0 = 0; p0 < NPB * TPN; p0 += BLK) {
        int p = p0 + threadIdx.x;
        int nl = p / TPN, q = p % TPN;
        int node = blockIdx.x * NPB + nl;
        float4 a0 = make_float4(0.f, 0.f, 0.f, 0.f);
        float4 a1 = make_float4(0.f, 0.f, 0.f, 0.f);
        if (node < N) {
            int s = offs[node], e = offs[node + 1];
            int j = s;
            for (; j + 4 <= e; j += 4) {
                int2 p0e = perm[j + 0], p1e = perm[j + 1];
                int2 p2e = perm[j + 2], p3e = perm[j + 3];
                ushort4 u0 = *(const ushort4*)(H + (long)p0e.x * K + q * 4);
                ushort4 u1 = *(const ushort4*)(H + (long)p1e.x * K + q * 4);
                ushort4 u2 = *(const ushort4*)(H + (long)p2e.x * K + q * 4);
                ushort4 u3 = *(const ushort4*)(H + (long)p3e.x * K + q * 4);
                ACC4(a0, u0, __int_as_float(p0e.y));
                ACC4(a1, u1, __int_as_float(p1e.y));
                ACC4(a0, u2, __int_as_float(p2e.y));
                ACC4(a1, u3, __int_as_float(p3e.y));
            }
            for (; j < e; ++j) {
                int2 pe = perm[j];
                ushort4 u = *(const ushort4*)(H + (long)pe.x * K + q * 4);
                ACC4(a0, u, __int_as_float(pe.y));
            }
            float di = dinv[node], d2 = di * di;
            ushort4 su = *(const ushort4*)(H + (long)node * K + q * 4);
            ACC4(a0, su, d2);
        }
        a0.x += a1.x; a0.y += a1.y; a0.z += a1.z; a0.w += a1.w;
        *(float4*)&aggs[nl * KP + q * 4] = a0;
    }
    __syncthreads();

    // ---- phase 2: gemm (W from global) + pool ----
    int q = threadIdx.x % TPQ, pg = threadIdx.x / TPQ;
    long nbase = (long)blockIdx.x * NPB + (long)pg * NPT;
    float4 acc[NPT];
#pragma unroll
    for (int t = 0; t < NPT; ++t) acc[t] = make_float4(0.f, 0.f, 0.f, 0.f);
    const float* wq = W + q * 4;
#pragma unroll 4
    for (int i = 0; i < K / 4; ++i) {
        float4 xv[NPT];
#pragma unroll
        for (int t = 0; t < NPT; ++t)
            xv[t] = *(const float4*)&aggs[(pg * NPT + t) * KP + i * 4];
#pragma unroll
        for (int j = 0; j < 4; ++j) {
            float4 wv = *(const float4*)(wq + (i * 4 + j) * FOUT);
#pragma unroll
            for (int t = 0; t < NPT; ++t) {
                float v = ((const float*)&xv[t])[j];
                acc[t].x += v * wv.x; acc[t].y += v * wv.y;
                acc[t].z += v * wv.z; acc[t].w += v * wv.w;
            }
        }
    }
    float4 bv = *(const float4*)(bias + q * 4);
#pragma unroll
    for (int t = 0; t < NPT; ++t) {
        long n = nbase + t;
        if (n < N) {
            unsigned int bx = __float_as_uint(fmaxf(acc[t].x + bv.x, 0.f));
            unsigned int by = __float_as_uint(fmaxf(acc[t].y + bv.y, 0.f));
            unsigned int bz = __float_as_uint(fmaxf(acc[t].z + bv.z, 0.f));
            unsigned int bw = __float_as_uint(fmaxf(acc[t].w + bv.w, 0.f));
            int rel = batch[n] - gfirst;
            if (rel < 2) {
                unsigned int* d = gma + rel * FOUT + q * 4;
                atomicMax(d + 0, bx); atomicMax(d + 1, by);
                atomicMax(d + 2, bz); atomicMax(d + 3, bw);
            } else {
                unsigned int* d = g + (long)batch[n] * FOUT + q * 4;
                atomicMax(d + 0, bx); atomicMax(d + 1, by);
                atomicMax(d + 2, bz); atomicMax(d + 3, bw);
            }
        }
    }
    __syncthreads();
    for (int i = threadIdx.x; i < 2 * FOUT; i += BLK) {
        unsigned int v = gma[i];
        if (v) atomicMax(&g[(long)(gfirst + i / FOUT) * FOUT + (i % FOUT)], v);
    }
}

// one block per graph: relu(g@Wfc1+bfc1) @ Wfc2 + bfc2 -> softmax
__global__ void fc_kernel(const float* __restrict__ g, const float* __restrict__ Wfc1,
                          const float* __restrict__ bfc1, const float* __restrict__ Wfc2,
                          const float* __restrict__ bfc2, float* __restrict__ out) {
    __shared__ float gs[128];
    __shared__ float red0[256], red1[256];
    int b = blockIdx.x, tid = threadIdx.x;
    if (tid < 128) gs[tid] = g[b * 128 + tid];
    __syncthreads();
    float h0 = bfc1[tid], h1 = bfc1[tid + 256];
    for (int k = 0; k < 128; ++k) {
        float gv = gs[k];
        h0 += gv * Wfc1[k * 512 + tid];
        h1 += gv * Wfc1[k * 512 + tid + 256];
    }
    h0 = fmaxf(h0, 0.f); h1 = fmaxf(h1, 0.f);
    red0[tid] = h0 * Wfc2[tid * 2 + 0] + h1 * Wfc2[(tid + 256) * 2 + 0];
    red1[tid] = h0 * Wfc2[tid * 2 + 1] + h1 * Wfc2[(tid + 256) * 2 + 1];
    __syncthreads();
    for (int s = 128; s > 0; s >>= 1) {
        if (tid < s) { red0[tid] += red0[tid + s]; red1[tid] += red1[tid + s]; }
        __syncthreads();
    }
    if (tid == 0) {
        float L0 = red0[0] + bfc2[0], L1 = red1[0] + bfc2[1];
        float m = fmaxf(L0, L1);
        float e0 = expf(L0 - m), e1 = expf(L1 - m);
        float inv = 1.f / (e0 + e1);
        out[b * 2 + 0] = e0 * inv;
        out[b * 2 + 1] = e1 * inv;
    }
}

extern "C" void kernel_launch(void* const* d_in, const int* in_sizes, int n_in,
                              void* d_out, int out_size, void* d_ws, size_t ws_size,
                              hipStream_t stream) {
    const float* x     = (const float*)d_in[0];
    const int*   ei    = (const int*)d_in[1];
    const float* ew    = (const float*)d_in[2];
    const int*   batch = (const int*)d_in[3];
    const float* W1    = (const float*)d_in[4];
    const float* b1    = (const float*)d_in[5];
    const float* W2    = (const float*)d_in[6];
    const float* b2    = (const float*)d_in[7];
    const float* W3    = (const float*)d_in[8];
    const float* b3    = (const float*)d_in[9];
    const float* Wfc1  = (const float*)d_in[10];
    const float* bfc1  = (const float*)d_in[11];
    const float* Wfc2  = (const float*)d_in[12];
    const float* bfc2  = (const float*)d_in[13];

    const int N = in_sizes[3];      // 100000
    const int E = in_sizes[2];      // 1600000
    const int* row = ei;
    const int* col = ei + E;

    char* ws = (char*)d_ws;
    float* dinv   = (float*)ws;              ws += align256((size_t)N * 4);
    int*   offs   = (int*)ws;                ws += align256((size_t)(N + 1) * 4);
    int*   bsums  = (int*)ws;                ws += align256((size_t)1024 * 4);
    int2*  perm   = (int2*)ws;               ws += align256((size_t)E * 8);
    float* bufA   = (float*)ws;              ws += align256((size_t)N * 128 * 4);  // build transients
    ushort* bufH1 = (ushort*)ws;             ws += align256((size_t)N * 40 * 2);   // H1 bf16
    ushort* bufH2 = (ushort*)ws;             ws += align256((size_t)N * 80 * 2);   // H2 bf16
    ushort* xbf   = (ushort*)ws;             ws += align256((size_t)N * 40 * 2);   // x bf16
    float* g      = (float*)ws;              ws += align256((size_t)512 * 128 * 4);

    const int NB   = cdiv(N, 64);            // 1563 buckets (<= MAXNB)
    const int TOT  = NB * TB;                // (bucket, tile) cells = 400128
    const int chunkE = cdiv(E, TB);          // edges per tile = 6250
    const int nScanH = cdiv(TOT, SCHUNK);    // 391 (<= 1024)

    // transients aliased into bufA (51.2MB; all dead before convs):
    // semi int2 (12.8MB) | gHist u32[TOT] (1.6MB) | scanned u32[TOT] (1.6MB)
    int2* semi = (int2*)bufA;
    unsigned int* gHist =
        (unsigned int*)((char*)bufA + align256((size_t)E * 8));
    unsigned int* scanned =
        (unsigned int*)((char*)gHist + align256((size_t)TOT * 4));

    const int B = 256;

    // --- atomic-free CSR build ---
    histA_kernel<<<TB, 512, 0, stream>>>(col, gHist, E, NB, chunkE,
                                         x, xbf, (long)N * 10);
    scanAH_kernel<<<nScanH, B, 0, stream>>>(gHist, bsums, TOT, NB);
    scanB_kernel<<<1, 1024, 0, stream>>>(bsums, offs, nScanH, N);
    scanCH_kernel<<<nScanH, B, 0, stream>>>(gHist, bsums, scanned, TOT, NB);
    scatterC_kernel<<<TB, 512, 0, stream>>>(row, col, ew, scanned, semi, E, NB, chunkE);
    fineD_kernel<<<NB, 256, 0, stream>>>(semi, scanned, offs, dinv, perm, E, N, NB);
    normE_kernel<<<cdiv(N, B), B, 0, stream>>>(offs, dinv, perm, N);

    // --- conv1 fused: H1 = relu((A*x)@W1 + b1) -> bufH1 (bf16) ---
    fused_conv_kernel<40, 40, 128, 320><<<cdiv(N, 128), 320, 0, stream>>>(
        offs, perm, xbf, dinv, W1, b1, bufH1, N);

    // --- conv2 fused: H2 = relu((A*H1)@W2 + b2) -> bufH2 (bf16) ---
    fused_conv_kernel<40, 80, 64, 320><<<cdiv(N, 64), 320, 0, stream>>>(
        offs, perm, bufH1, dinv, W2, b2, bufH2, N);

    // --- conv3 fused: pool(relu((A*H2)@W3 + b3)) -> g ---
    hipMemsetAsync(g, 0, (size_t)512 * 128 * 4, stream);
    fused_conv3_pool_kernel<80, 128, 64, 256><<<cdiv(N, 64), 256, 0, stream>>>(
        offs, perm, bufH2, dinv, W3, b3, batch, (unsigned int*)g, N);

    // --- MLP + softmax ---
    fc_kernel<<<512, 256, 0, stream>>>(g, Wfc1, bfc1, Wfc2, bfc2, (float*)d_out);
}

// Round 16
// 358.809 us; speedup vs baseline: 8.9617x; 1.0278x over previous
//
#include <hip/hip_runtime.h>

// ---------------------------------------------------------------------------
// GCNnet: 3x GCNConv (40->40->80->128) + global max pool + MLP(128->512->2) + softmax
// N=100000 nodes, E=1600000 edges, G=512 graphs.
// Round 24 (= R23 + compile fix: int cast in batch[min(...)]). conv3 overlap
// is unobtainable (6 structures, 102us floor) -> cut phase-2 cost instead:
// MFMA. agg stored bf16 in LDS (KS=96, k 80..95 zero, 12KB); W3 pre-packed
// bf16 W3p[(chunk*128+col)*32+k] (24.6KB, L2-hot); phase2 =
// v_mfma_f32_16x16x32_bf16: wave = 16-node strip, 8 col-tiles x 3 k-chunks
// = 24 MFMA (acc 32 VGPR). A-frag: row=l&15, k=(l>>4)*8 (one ds_read_b128
// per chunk); C/D: col=lane&15, row=(lane>>4)*4+reg (m89-verified).
// Phase-2 instr count drops ~20x; phase 1 unchanged (+bf16 store).
// ---------------------------------------------------------------------------

static inline int cdiv(long a, int b) { return (int)((a + b - 1) / b); }
static inline size_t align256(size_t x) { return (x + 255) & ~(size_t)255; }

#define FXSCALE 16777216.0f           // 2^24
#define SCHUNK  1024                  // elements per scan block
#define BKT_SHIFT 6                   // 64 nodes per bucket
#define MAXNB   2048                  // LDS histogram capacity (N <= 131072)
#define TB      256                   // histogram tiles

typedef __attribute__((ext_vector_type(8))) short bf16x8;
typedef __attribute__((ext_vector_type(4))) float f32x4;

__device__ __forceinline__ float bf2f(unsigned short u) {
    return __uint_as_float(((unsigned int)u) << 16);
}
__device__ __forceinline__ unsigned short f2bf(float f) {   // round-nearest-even
    unsigned int u = __float_as_uint(f);
    return (unsigned short)((u + 0x7FFFu + ((u >> 16) & 1u)) >> 16);
}

#define ACC4(A, U, M)                                                         \
    do {                                                                      \
        A.x += bf2f((U).x) * (M); A.y += bf2f((U).y) * (M);                   \
        A.z += bf2f((U).z) * (M); A.w += bf2f((U).w) * (M);                   \
    } while (0)

// Pass A: per-tile LDS histogram over NB buckets (bucket = col>>6).
// gHist[tile][bucket]. Fused: x f32 -> bf16 (unpadded rows, stride 40).
__global__ __launch_bounds__(512)
void histA_kernel(const int* __restrict__ col, unsigned int* __restrict__ gHist,
                  int E, int NB, int chunk,
                  const float* __restrict__ x, ushort* __restrict__ xbf, long n4) {
    __shared__ unsigned int hist[MAXNB];
    int t = blockIdx.x;
    for (int i = threadIdx.x; i < NB; i += 512) hist[i] = 0u;
    __syncthreads();
    int s = t * chunk, e = min(s + chunk, E);
    for (int i = s + threadIdx.x; i < e; i += 512)
        atomicAdd(&hist[(unsigned int)col[i] >> BKT_SHIFT], 1u);
    // fused f2bf: i/10 = row, i%10 = float4 slot -> xbf[row*40 + slot*4]
    long gid = (long)t * 512 + threadIdx.x, gstride = (long)TB * 512;
    for (long i = gid; i < n4; i += gstride) {
        float4 v = ((const float4*)x)[i];
        long r = i / 10, c = i % 10;
        *(ushort4*)(xbf + r * 40 + c * 4) =
            make_ushort4(f2bf(v.x), f2bf(v.y), f2bf(v.z), f2bf(v.w));
    }
    __syncthreads();
    for (int b = threadIdx.x; b < NB; b += 512)
        gHist[(size_t)t * NB + b] = hist[b];
}

// scan phase A (histogram variant): per-block sums of the bucket-major view
// element i -> gHist[(i&255)*NB + (i>>8)]   (i = bucket*256 + tile)
__global__ void scanAH_kernel(const unsigned int* __restrict__ gHist,
                              int* __restrict__ blockSums, int TOT, int NB) {
    __shared__ int wred[4];
    int tid = threadIdx.x, lane = tid & 63, wid = tid >> 6;
    int i0 = blockIdx.x * SCHUNK + tid * 4;
    int s = 0;
#pragma unroll
    for (int k = 0; k < 4; ++k) {
        int i = i0 + k;
        if (i < TOT) s += (int)gHist[(size_t)(i & 255) * NB + (i >> 8)];
    }
#pragma unroll
    for (int off = 32; off > 0; off >>= 1) s += __shfl_down(s, off, 64);
    if (lane == 0) wred[wid] = s;
    __syncthreads();
    if (tid == 0) blockSums[blockIdx.x] = wred[0] + wred[1] + wred[2] + wred[3];
}

// scan phase B: one block, exclusive scan of blockSums[nb] (nb <= 1024);
// writes grand total into offs[N] (= E).
__global__ void scanB_kernel(int* __restrict__ blockSums, int* __restrict__ offs,
                             int nb, int N) {
    __shared__ int wsum[16];
    int tid = threadIdx.x, lane = tid & 63, wid = tid >> 6;
    int v = (tid < nb) ? blockSums[tid] : 0;
    int incl = v;
#pragma unroll
    for (int off = 1; off < 64; off <<= 1) {
        int t = __shfl_up(incl, off, 64);
        if (lane >= off) incl += t;
    }
    if (lane == 63) wsum[wid] = incl;
    __syncthreads();
    if (wid == 0 && lane < 16) {
        int w = wsum[lane];
        int ic = w;
#pragma unroll
        for (int off = 1; off < 16; off <<= 1) {
            int t = __shfl_up(ic, off, 64);
            if (lane >= off) ic += t;
        }
        wsum[lane] = ic - w;   // exclusive
    }
    __syncthreads();
    if (tid < nb) blockSums[tid] = wsum[wid] + incl - v;   // exclusive prefix
    if (tid == 1023) offs[N] = wsum[15] + incl;            // grand total
}

// scan phase C (histogram variant): local exclusive scan + block offset ->
// scanned[i] = global output cursor for (bucket = i>>8, tile = i&255)
__global__ void scanCH_kernel(const unsigned int* __restrict__ gHist,
                              const int* __restrict__ blockSums,
                              unsigned int* __restrict__ scanned, int TOT, int NB) {
    __shared__ int wsum[4];
    int tid = threadIdx.x, lane = tid & 63, wid = tid >> 6;
    int i0 = blockIdx.x * SCHUNK + tid * 4;
    int v0 = 0, v1 = 0, v2 = 0, v3 = 0;
    if (i0 + 0 < TOT) v0 = (int)gHist[(size_t)((i0 + 0) & 255) * NB + ((i0 + 0) >> 8)];
    if (i0 + 1 < TOT) v1 = (int)gHist[(size_t)((i0 + 1) & 255) * NB + ((i0 + 1) >> 8)];
    if (i0 + 2 < TOT) v2 = (int)gHist[(size_t)((i0 + 2) & 255) * NB + ((i0 + 2) >> 8)];
    if (i0 + 3 < TOT) v3 = (int)gHist[(size_t)((i0 + 3) & 255) * NB + ((i0 + 3) >> 8)];
    int sum = v0 + v1 + v2 + v3;
    int incl = sum;
#pragma unroll
    for (int off = 1; off < 64; off <<= 1) {
        int t = __shfl_up(incl, off, 64);
        if (lane >= off) incl += t;
    }
    if (lane == 63) wsum[wid] = incl;
    __syncthreads();
    if (tid == 0) {
        int c = 0;
#pragma unroll
        for (int k = 0; k < 4; ++k) { int t = wsum[k]; wsum[k] = c; c += t; }
    }
    __syncthreads();
    int pre = blockSums[blockIdx.x] + wsum[wid] + (incl - sum);
    if (i0 + 0 < TOT) scanned[i0 + 0] = (unsigned int)pre;
    if (i0 + 1 < TOT) scanned[i0 + 1] = (unsigned int)(pre + v0);
    if (i0 + 2 < TOT) scanned[i0 + 2] = (unsigned int)(pre + v0 + v1);
    if (i0 + 3 < TOT) scanned[i0 + 3] = (unsigned int)(pre + v0 + v1 + v2);
}

// Pass C: scatter edges into bucket-grouped semi[] via LDS cursors.
// semi[pos] = {row | (col&63)<<17, wbits} (int2, row < 2^17).
__global__ __launch_bounds__(512)
void scatterC_kernel(const int* __restrict__ row, const int* __restrict__ col,
                     const float* __restrict__ w,
                     const unsigned int* __restrict__ scanned,
                     int2* __restrict__ semi, int E, int NB, int chunk) {
    __shared__ unsigned int cur[MAXNB];
    int t = blockIdx.x;
    for (int b = threadIdx.x; b < NB; b += 512)
        cur[b] = scanned[(size_t)b * TB + t];
    __syncthreads();
    int s = t * chunk, e = min(s + chunk, E);
    for (int i = s + threadIdx.x; i < e; i += 512) {
        int c = col[i];
        unsigned int pos = atomicAdd(&cur[(unsigned int)c >> BKT_SHIFT], 1u);
        semi[pos] = make_int2(row[i] | ((c & 63) << 17), __float_as_int(w[i]));
    }
}

// Pass D: one block per bucket (64 nodes). Fine counting sort by c6,
// per-node weighted degree (fixed-point LDS atomics) -> perm {row,wbits},
// offs, dinv. All atomics LDS.
__global__ __launch_bounds__(256)
void fineD_kernel(const int2* __restrict__ semi, const unsigned int* __restrict__ scanned,
                  int* __restrict__ offs, float* __restrict__ dinv,
                  int2* __restrict__ perm, int E, int N, int NB) {
    __shared__ unsigned int cnt[64], cur[64], wsum[64];
    __shared__ int nodeOffs[64];
    int b = blockIdx.x, tid = threadIdx.x;
    int s = (int)scanned[(size_t)b * TB];
    int e = (b + 1 < NB) ? (int)scanned[(size_t)(b + 1) * TB] : E;
    if (tid < 64) { cnt[tid] = 0u; wsum[tid] = 0u; }
    __syncthreads();
    for (int i = s + tid; i < e; i += 256) {
        int2 v = semi[i];
        int c6 = (v.x >> 17) & 63;
        atomicAdd(&cnt[c6], 1u);
        atomicAdd(&wsum[c6], (unsigned int)llrintf(__int_as_float(v.y) * FXSCALE));
    }
    __syncthreads();
    if (tid < 64) {
        int v = (int)cnt[tid];
        int incl = v;
#pragma unroll
        for (int off = 1; off < 64; off <<= 1) {
            int u = __shfl_up(incl, off, 64);
            if (tid >= off) incl += u;
        }
        nodeOffs[tid] = incl - v;          // exclusive within bucket
        cur[tid] = (unsigned int)(incl - v);
    }
    __syncthreads();
    for (int i = s + tid; i < e; i += 256) {
        int2 v = semi[i];
        int c6 = (v.x >> 17) & 63;
        unsigned int r = atomicAdd(&cur[c6], 1u);
        perm[s + (int)r] = make_int2(v.x & 0x1FFFF, v.y);   // {row, wbits}
    }
    if (tid < 64) {
        int node = (b << BKT_SHIFT) + tid;
        if (node < N) {
            offs[node] = s + nodeOffs[tid];
            float deg = (float)wsum[tid] * (1.0f / FXSCALE);
            dinv[node] = rsqrtf(deg + 1.0f);
        }
    }
    if (b == NB - 1 && tid == 0) offs[N] = E;
}

// Pass E: perm.y = dinv[row] * w * dinv[col]  (thread per destination node)
__global__ void normE_kernel(const int* __restrict__ offs, const float* __restrict__ dinv,
                             int2* __restrict__ perm, int N) {
    int n = blockIdx.x * blockDim.x + threadIdx.x;
    if (n >= N) return;
    int s = offs[n], e = offs[n + 1];
    float dc = dinv[n];
    for (int j = s; j < e; ++j) {
        int2 p = perm[j];
        float nm = dinv[p.x] * __int_as_float(p.y) * dc;
        perm[j] = make_int2(p.x, __float_as_int(nm));
    }
}

// W3 -> bf16 packed for MFMA B-fragments: W3p[(c*128+col)*32 + kk] =
// bf16(W3[c*32+kk][col]), zero for k >= 80. 3 chunks of K=32.
__global__ void w3prep_kernel(const float* __restrict__ W3, ushort* __restrict__ W3p) {
    int i = blockIdx.x * 256 + threadIdx.x;
    if (i >= 3 * 128 * 32) return;
    int kk = i & 31, c = i >> 12, colv = (i >> 5) & 127;
    int k = c * 32 + kk;
    float v = (k < 80) ? W3[k * 128 + colv] : 0.f;
    W3p[i] = f2bf(v);
}

// Fused conv (conv1/conv2): phase1 = R11 gather into LDS agg (rows padded to
// K+4 floats vs phase-2 bank conflicts); sync; phase2 = gemm from LDS, relu,
// bf16 out. Removes the bufA global round-trip entirely.
template<int K, int FOUT, int NPB, int BLK>
__global__ __launch_bounds__(BLK)
void fused_conv_kernel(const int* __restrict__ offs, const int2* __restrict__ perm,
                       const ushort* __restrict__ H, const float* __restrict__ dinv,
                       const float* __restrict__ W, const float* __restrict__ bias,
                       ushort* __restrict__ out, int N) {
    constexpr int TPN = K / 4;
    constexpr int TPQ = FOUT / 4;
    constexpr int NPT = 4;
    constexpr int KP = K + 4;              // padded agg row (floats)
    static_assert((NPB * TPN) % BLK == 0, "phase1 tiling");
    static_assert((NPB / NPT) * TPQ == BLK, "phase2 tiling");
    __shared__ float wsm[K * FOUT];
    __shared__ float aggs[NPB * KP];
    for (int i = threadIdx.x; i < K * FOUT; i += BLK) wsm[i] = W[i];

    // ---- phase 1: gather into LDS ----
#pragma unroll
    for (int p0 = 0; p0 < NPB * TPN; p0 += BLK) {
        int p = p0 + threadIdx.x;
        int nl = p / TPN, q = p % TPN;
        int node = blockIdx.x * NPB + nl;
        float4 a0 = make_float4(0.f, 0.f, 0.f, 0.f);
        float4 a1 = make_float4(0.f, 0.f, 0.f, 0.f);
        if (node < N) {
            int s = offs[node], e = offs[node + 1];
            int j = s;
            for (; j + 4 <= e; j += 4) {
                int2 p0e = perm[j + 0], p1e = perm[j + 1];
                int2 p2e = perm[j + 2], p3e = perm[j + 3];
                ushort4 u0 = *(const ushort4*)(H + (long)p0e.x * K + q * 4);
                ushort4 u1 = *(const ushort4*)(H + (long)p1e.x * K + q * 4);
                ushort4 u2 = *(const ushort4*)(H + (long)p2e.x * K + q * 4);
                ushort4 u3 = *(const ushort4*)(H + (long)p3e.x * K + q * 4);
                ACC4(a0, u0, __int_as_float(p0e.y));
                ACC4(a1, u1, __int_as_float(p1e.y));
                ACC4(a0, u2, __int_as_float(p2e.y));
                ACC4(a1, u3, __int_as_float(p3e.y));
            }
            for (; j < e; ++j) {
                int2 pe = perm[j];
                ushort4 u = *(const ushort4*)(H + (long)pe.x * K + q * 4);
                ACC4(a0, u, __int_as_float(pe.y));
            }
            float di = dinv[node], d2 = di * di;
            ushort4 su = *(const ushort4*)(H + (long)node * K + q * 4);
            ACC4(a0, su, d2);
        }
        a0.x += a1.x; a0.y += a1.y; a0.z += a1.z; a0.w += a1.w;
        *(float4*)&aggs[nl * KP + q * 4] = a0;
    }
    __syncthreads();

    // ---- phase 2: gemm from LDS ----
    int q = threadIdx.x % TPQ, pg = threadIdx.x / TPQ;
    long nbase = (long)blockIdx.x * NPB + (long)pg * NPT;
    float4 acc[NPT];
#pragma unroll
    for (int t = 0; t < NPT; ++t) acc[t] = make_float4(0.f, 0.f, 0.f, 0.f);
    const float* wq = wsm + q * 4;
#pragma unroll 4
    for (int i = 0; i < K / 4; ++i) {
        float4 xv[NPT];
#pragma unroll
        for (int t = 0; t < NPT; ++t)
            xv[t] = *(const float4*)&aggs[(pg * NPT + t) * KP + i * 4];
#pragma unroll
        for (int j = 0; j < 4; ++j) {
            float4 wv = *(const float4*)(wq + (i * 4 + j) * FOUT);
#pragma unroll
            for (int t = 0; t < NPT; ++t) {
                float v = ((const float*)&xv[t])[j];
                acc[t].x += v * wv.x; acc[t].y += v * wv.y;
                acc[t].z += v * wv.z; acc[t].w += v * wv.w;
            }
        }
    }
    float4 bv = *(const float4*)(bias + q * 4);
#pragma unroll
    for (int t = 0; t < NPT; ++t) {
        long n = nbase + t;
        if (n < N) {
            float ox = fmaxf(acc[t].x + bv.x, 0.f);
            float oy = fmaxf(acc[t].y + bv.y, 0.f);
            float oz = fmaxf(acc[t].z + bv.z, 0.f);
            float ow = fmaxf(acc[t].w + bv.w, 0.f);
            *(ushort4*)(out + n * FOUT + q * 4) =
                make_ushort4(f2bf(ox), f2bf(oy), f2bf(oz), f2bf(ow));
        }
    }
}

// Fused conv3 + pool (MFMA phase 2): phase1 = gather NPB=64 nodes x 80 feats
// into LDS as bf16 (KS=96 ushorts, k 80..95 zero; 12KB); phase2 = per-wave
// 16-node strip, 8 col-tiles x 3 k-chunks of v_mfma_f32_16x16x32_bf16 with
// B from packed W3p (global, L2-hot) + relu + hierarchical max-pool.
template<int K, int FOUT, int NPB, int BLK>   // 80, 128, 64, 256
__global__ __launch_bounds__(BLK)
void fused_conv3_pool_kernel(const int* __restrict__ offs, const int2* __restrict__ perm,
                             const ushort* __restrict__ H, const float* __restrict__ dinv,
                             const ushort* __restrict__ W3p, const float* __restrict__ bias,
                             const int* __restrict__ batch,
                             unsigned int* __restrict__ g, int N) {
    constexpr int TPN = K / 4;             // 20 gather slots per node
    constexpr int KS = 96;                 // LDS row stride (ushorts), 3x32
    static_assert((NPB * TPN) % BLK == 0, "phase1 tiling");
    static_assert(NPB == 64 && BLK == 256 && FOUT == 128, "mfma tiling");
    __shared__ ushort aggs[NPB * KS];      // bf16 agg, 12KB
    __shared__ unsigned int gma[2 * FOUT];
    __shared__ int sb[NPB];                // batch ids for block's nodes
    __shared__ int gfirst;
    int bb = blockIdx.x * NPB;
    int tid = (int)threadIdx.x;
    if (tid == 0) gfirst = batch[min(bb, N - 1)];
    if (tid < NPB) sb[tid] = batch[min(bb + tid, N - 1)];
    for (int i = tid; i < 2 * FOUT; i += BLK) gma[i] = 0u;
    // zero-fill pad region k=80..95: 64 nodes x 16 ushorts = 256 ushort4
    {
        int nl = tid >> 2, part = tid & 3;
        *(ushort4*)&aggs[nl * KS + 80 + part * 4] = make_ushort4(0, 0, 0, 0);
    }

    // ---- phase 1: gather into LDS (bf16) ----
#pragma unroll
    for (int p0 = 0; p0 < NPB * TPN; p0 += BLK) {
        int p = p0 + tid;
        int nl = p / TPN, q = p % TPN;
        int node = bb + nl;
        float4 a0 = make_float4(0.f, 0.f, 0.f, 0.f);
        float4 a1 = make_float4(0.f, 0.f, 0.f, 0.f);
        if (node < N) {
            int s = offs[node], e = offs[node + 1];
            int j = s;
            for (; j + 4 <= e; j += 4) {
                int2 p0e = perm[j + 0], p1e = perm[j + 1];
                int2 p2e = perm[j + 2], p3e = perm[j + 3];
                ushort4 u0 = *(const ushort4*)(H + (long)p0e.x * K + q * 4);
                ushort4 u1 = *(const ushort4*)(H + (long)p1e.x * K + q * 4);
                ushort4 u2 = *(const ushort4*)(H + (long)p2e.x * K + q * 4);
                ushort4 u3 = *(const ushort4*)(H + (long)p3e.x * K + q * 4);
                ACC4(a0, u0, __int_as_float(p0e.y));
                ACC4(a1, u1, __int_as_float(p1e.y));
                ACC4(a0, u2, __int_as_float(p2e.y));
                ACC4(a1, u3, __int_as_float(p3e.y));
            }
            for (; j < e; ++j) {
                int2 pe = perm[j];
                ushort4 u = *(const ushort4*)(H + (long)pe.x * K + q * 4);
                ACC4(a0, u, __int_as_float(pe.y));
            }
            float di = dinv[node], d2 = di * di;
            ushort4 su = *(const ushort4*)(H + (long)node * K + q * 4);
            ACC4(a0, su, d2);
        }
        a0.x += a1.x; a0.y += a1.y; a0.z += a1.z; a0.w += a1.w;
        *(ushort4*)&aggs[nl * KS + q * 4] =
            make_ushort4(f2bf(a0.x), f2bf(a0.y), f2bf(a0.z), f2bf(a0.w));
    }
    __syncthreads();

    // ---- phase 2: MFMA gemm + pool ----
    int lane = tid & 63, w = tid >> 6;     // 4 waves, 16 rows each
    int la = lane & 15, kg = lane >> 4;
    f32x4 acc[8];
#pragma unroll
    for (int t = 0; t < 8; ++t) acc[t] = (f32x4){0.f, 0.f, 0.f, 0.f};
#pragma unroll
    for (int c = 0; c < 3; ++c) {
        bf16x8 a = *(const bf16x8*)&aggs[(w * 16 + la) * KS + c * 32 + kg * 8];
        const ushort* bp = W3p + (size_t)c * 4096 + la * 32 + kg * 8;
#pragma unroll
        for (int t = 0; t < 8; ++t) {
            bf16x8 b = *(const bf16x8*)(bp + t * 512);
            acc[t] = __builtin_amdgcn_mfma_f32_16x16x32_bf16(a, b, acc[t], 0, 0, 0);
        }
    }
    // C/D: col = t*16 + (lane&15), row = w*16 + (lane>>4)*4 + r
    int rowg = w * 16 + kg * 4;
#pragma unroll
    for (int t = 0; t < 8; ++t) {
        int colv = t * 16 + la;
        float bvv = bias[colv];
#pragma unroll
        for (int r = 0; r < 4; ++r) {
            int nl = rowg + r;
            long node = (long)bb + nl;
            if (node < N) {
                float v = fmaxf(acc[t][r] + bvv, 0.f);
                unsigned int uv = __float_as_uint(v);
                int bn = sb[nl];
                int rel = bn - gfirst;
                if (rel < 2) atomicMax(&gma[rel * FOUT + colv], uv);
                else atomicMax(&g[(long)bn * FOUT + colv], uv);
            }
        }
    }
    __syncthreads();
    for (int i = tid; i < 2 * FOUT; i += BLK) {
        unsigned int v = gma[i];
        if (v) atomicMax(&g[(long)(gfirst + i / FOUT) * FOUT + (i % FOUT)], v);
    }
}

// one block per graph: relu(g@Wfc1+bfc1) @ Wfc2 + bfc2 -> softmax
__global__ void fc_kernel(const float* __restrict__ g, const float* __restrict__ Wfc1,
                          const float* __restrict__ bfc1, const float* __restrict__ Wfc2,
                          const float* __restrict__ bfc2, float* __restrict__ out) {
    __shared__ float gs[128];
    __shared__ float red0[256], red1[256];
    int b = blockIdx.x, tid = threadIdx.x;
    if (tid < 128) gs[tid] = g[b * 128 + tid];
    __syncthreads();
    float h0 = bfc1[tid], h1 = bfc1[tid + 256];
    for (int k = 0; k < 128; ++k) {
        float gv = gs[k];
        h0 += gv * Wfc1[k * 512 + tid];
        h1 += gv * Wfc1[k * 512 + tid + 256];
    }
    h0 = fmaxf(h0, 0.f); h1 = fmaxf(h1, 0.f);
    red0[tid] = h0 * Wfc2[tid * 2 + 0] + h1 * Wfc2[(tid + 256) * 2 + 0];
    red1[tid] = h0 * Wfc2[tid * 2 + 1] + h1 * Wfc2[(tid + 256) * 2 + 1];
    __syncthreads();
    for (int s = 128; s > 0; s >>= 1) {
        if (tid < s) { red0[tid] += red0[tid + s]; red1[tid] += red1[tid + s]; }
        __syncthreads();
    }
    if (tid == 0) {
        float L0 = red0[0] + bfc2[0], L1 = red1[0] + bfc2[1];
        float m = fmaxf(L0, L1);
        float e0 = expf(L0 - m), e1 = expf(L1 - m);
        float inv = 1.f / (e0 + e1);
        out[b * 2 + 0] = e0 * inv;
        out[b * 2 + 1] = e1 * inv;
    }
}

extern "C" void kernel_launch(void* const* d_in, const int* in_sizes, int n_in,
                              void* d_out, int out_size, void* d_ws, size_t ws_size,
                              hipStream_t stream) {
    const float* x     = (const float*)d_in[0];
    const int*   ei    = (const int*)d_in[1];
    const float* ew    = (const float*)d_in[2];
    const int*   batch = (const int*)d_in[3];
    const float* W1    = (const float*)d_in[4];
    const float* b1    = (const float*)d_in[5];
    const float* W2    = (const float*)d_in[6];
    const float* b2    = (const float*)d_in[7];
    const float* W3    = (const float*)d_in[8];
    const float* b3    = (const float*)d_in[9];
    const float* Wfc1  = (const float*)d_in[10];
    const float* bfc1  = (const float*)d_in[11];
    const float* Wfc2  = (const float*)d_in[12];
    const float* bfc2  = (const float*)d_in[13];

    const int N = in_sizes[3];      // 100000
    const int E = in_sizes[2];      // 1600000
    const int* row = ei;
    const int* col = ei + E;

    char* ws = (char*)d_ws;
    float* dinv   = (float*)ws;              ws += align256((size_t)N * 4);
    int*   offs   = (int*)ws;                ws += align256((size_t)(N + 1) * 4);
    int*   bsums  = (int*)ws;                ws += align256((size_t)1024 * 4);
    int2*  perm   = (int2*)ws;               ws += align256((size_t)E * 8);
    float* bufA   = (float*)ws;              ws += align256((size_t)N * 128 * 4);  // build transients
    ushort* bufH1 = (ushort*)ws;             ws += align256((size_t)N * 40 * 2);   // H1 bf16
    ushort* bufH2 = (ushort*)ws;             ws += align256((size_t)N * 80 * 2);   // H2 bf16
    ushort* xbf   = (ushort*)ws;             ws += align256((size_t)N * 40 * 2);   // x bf16
    float* g      = (float*)ws;              ws += align256((size_t)512 * 128 * 4);
    ushort* W3p   = (ushort*)ws;             ws += align256((size_t)3 * 128 * 32 * 2);

    const int NB   = cdiv(N, 64);            // 1563 buckets (<= MAXNB)
    const int TOT  = NB * TB;                // (bucket, tile) cells = 400128
    const int chunkE = cdiv(E, TB);          // edges per tile = 6250
    const int nScanH = cdiv(TOT, SCHUNK);    // 391 (<= 1024)

    // transients aliased into bufA (51.2MB; all dead before convs):
    // semi int2 (12.8MB) | gHist u32[TOT] (1.6MB) | scanned u32[TOT] (1.6MB)
    int2* semi = (int2*)bufA;
    unsigned int* gHist =
        (unsigned int*)((char*)bufA + align256((size_t)E * 8));
    unsigned int* scanned =
        (unsigned int*)((char*)gHist + align256((size_t)TOT * 4));

    const int B = 256;

    // --- atomic-free CSR build ---
    histA_kernel<<<TB, 512, 0, stream>>>(col, gHist, E, NB, chunkE,
                                         x, xbf, (long)N * 10);
    scanAH_kernel<<<nScanH, B, 0, stream>>>(gHist, bsums, TOT, NB);
    scanB_kernel<<<1, 1024, 0, stream>>>(bsums, offs, nScanH, N);
    scanCH_kernel<<<nScanH, B, 0, stream>>>(gHist, bsums, scanned, TOT, NB);
    scatterC_kernel<<<TB, 512, 0, stream>>>(row, col, ew, scanned, semi, E, NB, chunkE);
    fineD_kernel<<<NB, 256, 0, stream>>>(semi, scanned, offs, dinv, perm, E, N, NB);
    normE_kernel<<<cdiv(N, B), B, 0, stream>>>(offs, dinv, perm, N);
    w3prep_kernel<<<48, 256, 0, stream>>>(W3, W3p);

    // --- conv1 fused: H1 = relu((A*x)@W1 + b1) -> bufH1 (bf16) ---
    fused_conv_kernel<40, 40, 128, 320><<<cdiv(N, 128), 320, 0, stream>>>(
        offs, perm, xbf, dinv, W1, b1, bufH1, N);

    // --- conv2 fused: H2 = relu((A*H1)@W2 + b2) -> bufH2 (bf16) ---
    fused_conv_kernel<40, 80, 64, 320><<<cdiv(N, 64), 320, 0, stream>>>(
        offs, perm, bufH1, dinv, W2, b2, bufH2, N);

    // --- conv3 fused (MFMA phase 2): pool(relu((A*H2)@W3 + b3)) -> g ---
    hipMemsetAsync(g, 0, (size_t)512 * 128 * 4, stream);
    fused_conv3_pool_kernel<80, 128, 64, 256><<<cdiv(N, 64), 256, 0, stream>>>(
        offs, perm, bufH2, dinv, W3p, b3, batch, (unsigned int*)g, N);

    // --- MLP + softmax ---
    fc_kernel<<<512, 256, 0, stream>>>(g, Wfc1, bfc1, Wfc2, bfc2, (float*)d_out);
}

// Round 18
// 350.794 us; speedup vs baseline: 9.1665x; 1.0228x over previous
//
#include <hip/hip_runtime.h>

// ---------------------------------------------------------------------------
// GCNnet: 3x GCNConv (40->40->80->128) + global max pool + MLP(128->512->2) + softmax
// N=100000 nodes, E=1600000 edges, G=512 graphs.
// Round 26 (= R25 + copy-count fix): R25's LDS copy moved 768 ushort4 = HALF
// the 64x96 bf16 tile (1536 ushort4) -> rows 32-63 garbage -> absmax 0.49.
// Fix: copy as uint4 (16B): 12288B / 16 = 768 = 3/thread, correct count.
// Structure: split conv3 = gather_bf16 (R11 body, 57us-class, bf16 padded
// agg rows) + conv3_mfma_pool (uniform coalesced copy -> 24 MFMA/wave
// (R24-verified layout) -> hierarchical pool).
// ---------------------------------------------------------------------------

static inline int cdiv(long a, int b) { return (int)((a + b - 1) / b); }
static inline size_t align256(size_t x) { return (x + 255) & ~(size_t)255; }

#define FXSCALE 16777216.0f           // 2^24
#define SCHUNK  1024                  // elements per scan block
#define BKT_SHIFT 6                   // 64 nodes per bucket
#define MAXNB   2048                  // LDS histogram capacity (N <= 131072)
#define TB      256                   // histogram tiles

typedef __attribute__((ext_vector_type(8))) short bf16x8;
typedef __attribute__((ext_vector_type(4))) float f32x4;

__device__ __forceinline__ float bf2f(unsigned short u) {
    return __uint_as_float(((unsigned int)u) << 16);
}
__device__ __forceinline__ unsigned short f2bf(float f) {   // round-nearest-even
    unsigned int u = __float_as_uint(f);
    return (unsigned short)((u + 0x7FFFu + ((u >> 16) & 1u)) >> 16);
}

#define ACC4(A, U, M)                                                         \
    do {                                                                      \
        A.x += bf2f((U).x) * (M); A.y += bf2f((U).y) * (M);                   \
        A.z += bf2f((U).z) * (M); A.w += bf2f((U).w) * (M);                   \
    } while (0)

// Pass A: per-tile LDS histogram over NB buckets (bucket = col>>6).
// gHist[tile][bucket]. Fused: x f32 -> bf16 (unpadded rows, stride 40).
__global__ __launch_bounds__(512)
void histA_kernel(const int* __restrict__ col, unsigned int* __restrict__ gHist,
                  int E, int NB, int chunk,
                  const float* __restrict__ x, ushort* __restrict__ xbf, long n4) {
    __shared__ unsigned int hist[MAXNB];
    int t = blockIdx.x;
    for (int i = threadIdx.x; i < NB; i += 512) hist[i] = 0u;
    __syncthreads();
    int s = t * chunk, e = min(s + chunk, E);
    for (int i = s + threadIdx.x; i < e; i += 512)
        atomicAdd(&hist[(unsigned int)col[i] >> BKT_SHIFT], 1u);
    // fused f2bf: i/10 = row, i%10 = float4 slot -> xbf[row*40 + slot*4]
    long gid = (long)t * 512 + threadIdx.x, gstride = (long)TB * 512;
    for (long i = gid; i < n4; i += gstride) {
        float4 v = ((const float4*)x)[i];
        long r = i / 10, c = i % 10;
        *(ushort4*)(xbf + r * 40 + c * 4) =
            make_ushort4(f2bf(v.x), f2bf(v.y), f2bf(v.z), f2bf(v.w));
    }
    __syncthreads();
    for (int b = threadIdx.x; b < NB; b += 512)
        gHist[(size_t)t * NB + b] = hist[b];
}

// scan phase A (histogram variant): per-block sums of the bucket-major view
// element i -> gHist[(i&255)*NB + (i>>8)]   (i = bucket*256 + tile)
__global__ void scanAH_kernel(const unsigned int* __restrict__ gHist,
                              int* __restrict__ blockSums, int TOT, int NB) {
    __shared__ int wred[4];
    int tid = threadIdx.x, lane = tid & 63, wid = tid >> 6;
    int i0 = blockIdx.x * SCHUNK + tid * 4;
    int s = 0;
#pragma unroll
    for (int k = 0; k < 4; ++k) {
        int i = i0 + k;
        if (i < TOT) s += (int)gHist[(size_t)(i & 255) * NB + (i >> 8)];
    }
#pragma unroll
    for (int off = 32; off > 0; off >>= 1) s += __shfl_down(s, off, 64);
    if (lane == 0) wred[wid] = s;
    __syncthreads();
    if (tid == 0) blockSums[blockIdx.x] = wred[0] + wred[1] + wred[2] + wred[3];
}

// scan phase B: one block, exclusive scan of blockSums[nb] (nb <= 1024);
// writes grand total into offs[N] (= E).
__global__ void scanB_kernel(int* __restrict__ blockSums, int* __restrict__ offs,
                             int nb, int N) {
    __shared__ int wsum[16];
    int tid = threadIdx.x, lane = tid & 63, wid = tid >> 6;
    int v = (tid < nb) ? blockSums[tid] : 0;
    int incl = v;
#pragma unroll
    for (int off = 1; off < 64; off <<= 1) {
        int t = __shfl_up(incl, off, 64);
        if (lane >= off) incl += t;
    }
    if (lane == 63) wsum[wid] = incl;
    __syncthreads();
    if (wid == 0 && lane < 16) {
        int w = wsum[lane];
        int ic = w;
#pragma unroll
        for (int off = 1; off < 16; off <<= 1) {
            int t = __shfl_up(ic, off, 64);
            if (lane >= off) ic += t;
        }
        wsum[lane] = ic - w;   // exclusive
    }
    __syncthreads();
    if (tid < nb) blockSums[tid] = wsum[wid] + incl - v;   // exclusive prefix
    if (tid == 1023) offs[N] = wsum[15] + incl;            // grand total
}

// scan phase C (histogram variant): local exclusive scan + block offset ->
// scanned[i] = global output cursor for (bucket = i>>8, tile = i&255)
__global__ void scanCH_kernel(const unsigned int* __restrict__ gHist,
                              const int* __restrict__ blockSums,
                              unsigned int* __restrict__ scanned, int TOT, int NB) {
    __shared__ int wsum[4];
    int tid = threadIdx.x, lane = tid & 63, wid = tid >> 6;
    int i0 = blockIdx.x * SCHUNK + tid * 4;
    int v0 = 0, v1 = 0, v2 = 0, v3 = 0;
    if (i0 + 0 < TOT) v0 = (int)gHist[(size_t)((i0 + 0) & 255) * NB + ((i0 + 0) >> 8)];
    if (i0 + 1 < TOT) v1 = (int)gHist[(size_t)((i0 + 1) & 255) * NB + ((i0 + 1) >> 8)];
    if (i0 + 2 < TOT) v2 = (int)gHist[(size_t)((i0 + 2) & 255) * NB + ((i0 + 2) >> 8)];
    if (i0 + 3 < TOT) v3 = (int)gHist[(size_t)((i0 + 3) & 255) * NB + ((i0 + 3) >> 8)];
    int sum = v0 + v1 + v2 + v3;
    int incl = sum;
#pragma unroll
    for (int off = 1; off < 64; off <<= 1) {
        int t = __shfl_up(incl, off, 64);
        if (lane >= off) incl += t;
    }
    if (lane == 63) wsum[wid] = incl;
    __syncthreads();
    if (tid == 0) {
        int c = 0;
#pragma unroll
        for (int k = 0; k < 4; ++k) { int t = wsum[k]; wsum[k] = c; c += t; }
    }
    __syncthreads();
    int pre = blockSums[blockIdx.x] + wsum[wid] + (incl - sum);
    if (i0 + 0 < TOT) scanned[i0 + 0] = (unsigned int)pre;
    if (i0 + 1 < TOT) scanned[i0 + 1] = (unsigned int)(pre + v0);
    if (i0 + 2 < TOT) scanned[i0 + 2] = (unsigned int)(pre + v0 + v1);
    if (i0 + 3 < TOT) scanned[i0 + 3] = (unsigned int)(pre + v0 + v1 + v2);
}

// Pass C: scatter edges into bucket-grouped semi[] via LDS cursors.
// semi[pos] = {row | (col&63)<<17, wbits} (int2, row < 2^17).
__global__ __launch_bounds__(512)
void scatterC_kernel(const int* __restrict__ row, const int* __restrict__ col,
                     const float* __restrict__ w,
                     const unsigned int* __restrict__ scanned,
                     int2* __restrict__ semi, int E, int NB, int chunk) {
    __shared__ unsigned int cur[MAXNB];
    int t = blockIdx.x;
    for (int b = threadIdx.x; b < NB; b += 512)
        cur[b] = scanned[(size_t)b * TB + t];
    __syncthreads();
    int s = t * chunk, e = min(s + chunk, E);
    for (int i = s + threadIdx.x; i < e; i += 512) {
        int c = col[i];
        unsigned int pos = atomicAdd(&cur[(unsigned int)c >> BKT_SHIFT], 1u);
        semi[pos] = make_int2(row[i] | ((c & 63) << 17), __float_as_int(w[i]));
    }
}

// Pass D: one block per bucket (64 nodes). Fine counting sort by c6,
// per-node weighted degree (fixed-point LDS atomics) -> perm {row,wbits},
// offs, dinv. All atomics LDS.
__global__ __launch_bounds__(256)
void fineD_kernel(const int2* __restrict__ semi, const unsigned int* __restrict__ scanned,
                  int* __restrict__ offs, float* __restrict__ dinv,
                  int2* __restrict__ perm, int E, int N, int NB) {
    __shared__ unsigned int cnt[64], cur[64], wsum[64];
    __shared__ int nodeOffs[64];
    int b = blockIdx.x, tid = threadIdx.x;
    int s = (int)scanned[(size_t)b * TB];
    int e = (b + 1 < NB) ? (int)scanned[(size_t)(b + 1) * TB] : E;
    if (tid < 64) { cnt[tid] = 0u; wsum[tid] = 0u; }
    __syncthreads();
    for (int i = s + tid; i < e; i += 256) {
        int2 v = semi[i];
        int c6 = (v.x >> 17) & 63;
        atomicAdd(&cnt[c6], 1u);
        atomicAdd(&wsum[c6], (unsigned int)llrintf(__int_as_float(v.y) * FXSCALE));
    }
    __syncthreads();
    if (tid < 64) {
        int v = (int)cnt[tid];
        int incl = v;
#pragma unroll
        for (int off = 1; off < 64; off <<= 1) {
            int u = __shfl_up(incl, off, 64);
            if (tid >= off) incl += u;
        }
        nodeOffs[tid] = incl - v;          // exclusive within bucket
        cur[tid] = (unsigned int)(incl - v);
    }
    __syncthreads();
    for (int i = s + tid; i < e; i += 256) {
        int2 v = semi[i];
        int c6 = (v.x >> 17) & 63;
        unsigned int r = atomicAdd(&cur[c6], 1u);
        perm[s + (int)r] = make_int2(v.x & 0x1FFFF, v.y);   // {row, wbits}
    }
    if (tid < 64) {
        int node = (b << BKT_SHIFT) + tid;
        if (node < N) {
            offs[node] = s + nodeOffs[tid];
            float deg = (float)wsum[tid] * (1.0f / FXSCALE);
            dinv[node] = rsqrtf(deg + 1.0f);
        }
    }
    if (b == NB - 1 && tid == 0) offs[N] = E;
}

// Pass E: perm.y = dinv[row] * w * dinv[col]  (thread per destination node)
__global__ void normE_kernel(const int* __restrict__ offs, const float* __restrict__ dinv,
                             int2* __restrict__ perm, int N) {
    int n = blockIdx.x * blockDim.x + threadIdx.x;
    if (n >= N) return;
    int s = offs[n], e = offs[n + 1];
    float dc = dinv[n];
    for (int j = s; j < e; ++j) {
        int2 p = perm[j];
        float nm = dinv[p.x] * __int_as_float(p.y) * dc;
        perm[j] = make_int2(p.x, __float_as_int(nm));
    }
}

// W3 -> bf16 packed for MFMA B-fragments: W3p[(c*128+col)*32 + kk] =
// bf16(W3[c*32+kk][col]), zero for k >= 80. 3 chunks of K=32.
__global__ void w3prep_kernel(const float* __restrict__ W3, ushort* __restrict__ W3p) {
    int i = blockIdx.x * 256 + threadIdx.x;
    if (i >= 3 * 128 * 32) return;
    int kk = i & 31, c = i >> 12, colv = (i >> 5) & 127;
    int k = c * 32 + kk;
    float v = (k < 80) ? W3[k * 128 + colv] : 0.f;
    W3p[i] = f2bf(v);
}

// Fused conv (conv1/conv2): phase1 = R11 gather into LDS agg (rows padded to
// K+4 floats vs phase-2 bank conflicts); sync; phase2 = gemm from LDS, relu,
// bf16 out. Removes the bufA global round-trip entirely.
template<int K, int FOUT, int NPB, int BLK>
__global__ __launch_bounds__(BLK)
void fused_conv_kernel(const int* __restrict__ offs, const int2* __restrict__ perm,
                       const ushort* __restrict__ H, const float* __restrict__ dinv,
                       const float* __restrict__ W, const float* __restrict__ bias,
                       ushort* __restrict__ out, int N) {
    constexpr int TPN = K / 4;
    constexpr int TPQ = FOUT / 4;
    constexpr int NPT = 4;
    constexpr int KP = K + 4;              // padded agg row (floats)
    static_assert((NPB * TPN) % BLK == 0, "phase1 tiling");
    static_assert((NPB / NPT) * TPQ == BLK, "phase2 tiling");
    __shared__ float wsm[K * FOUT];
    __shared__ float aggs[NPB * KP];
    for (int i = threadIdx.x; i < K * FOUT; i += BLK) wsm[i] = W[i];

    // ---- phase 1: gather into LDS ----
#pragma unroll
    for (int p0 = 0; p0 < NPB * TPN; p0 += BLK) {
        int p = p0 + threadIdx.x;
        int nl = p / TPN, q = p % TPN;
        int node = blockIdx.x * NPB + nl;
        float4 a0 = make_float4(0.f, 0.f, 0.f, 0.f);
        float4 a1 = make_float4(0.f, 0.f, 0.f, 0.f);
        if (node < N) {
            int s = offs[node], e = offs[node + 1];
            int j = s;
            for (; j + 4 <= e; j += 4) {
                int2 p0e = perm[j + 0], p1e = perm[j + 1];
                int2 p2e = perm[j + 2], p3e = perm[j + 3];
                ushort4 u0 = *(const ushort4*)(H + (long)p0e.x * K + q * 4);
                ushort4 u1 = *(const ushort4*)(H + (long)p1e.x * K + q * 4);
                ushort4 u2 = *(const ushort4*)(H + (long)p2e.x * K + q * 4);
                ushort4 u3 = *(const ushort4*)(H + (long)p3e.x * K + q * 4);
                ACC4(a0, u0, __int_as_float(p0e.y));
                ACC4(a1, u1, __int_as_float(p1e.y));
                ACC4(a0, u2, __int_as_float(p2e.y));
                ACC4(a1, u3, __int_as_float(p3e.y));
            }
            for (; j < e; ++j) {
                int2 pe = perm[j];
                ushort4 u = *(const ushort4*)(H + (long)pe.x * K + q * 4);
                ACC4(a0, u, __int_as_float(pe.y));
            }
            float di = dinv[node], d2 = di * di;
            ushort4 su = *(const ushort4*)(H + (long)node * K + q * 4);
            ACC4(a0, su, d2);
        }
        a0.x += a1.x; a0.y += a1.y; a0.z += a1.z; a0.w += a1.w;
        *(float4*)&aggs[nl * KP + q * 4] = a0;
    }
    __syncthreads();

    // ---- phase 2: gemm from LDS ----
    int q = threadIdx.x % TPQ, pg = threadIdx.x / TPQ;
    long nbase = (long)blockIdx.x * NPB + (long)pg * NPT;
    float4 acc[NPT];
#pragma unroll
    for (int t = 0; t < NPT; ++t) acc[t] = make_float4(0.f, 0.f, 0.f, 0.f);
    const float* wq = wsm + q * 4;
#pragma unroll 4
    for (int i = 0; i < K / 4; ++i) {
        float4 xv[NPT];
#pragma unroll
        for (int t = 0; t < NPT; ++t)
            xv[t] = *(const float4*)&aggs[(pg * NPT + t) * KP + i * 4];
#pragma unroll
        for (int j = 0; j < 4; ++j) {
            float4 wv = *(const float4*)(wq + (i * 4 + j) * FOUT);
#pragma unroll
            for (int t = 0; t < NPT; ++t) {
                float v = ((const float*)&xv[t])[j];
                acc[t].x += v * wv.x; acc[t].y += v * wv.y;
                acc[t].z += v * wv.z; acc[t].w += v * wv.w;
            }
        }
    }
    float4 bv = *(const float4*)(bias + q * 4);
#pragma unroll
    for (int t = 0; t < NPT; ++t) {
        long n = nbase + t;
        if (n < N) {
            float ox = fmaxf(acc[t].x + bv.x, 0.f);
            float oy = fmaxf(acc[t].y + bv.y, 0.f);
            float oz = fmaxf(acc[t].z + bv.z, 0.f);
            float ow = fmaxf(acc[t].w + bv.w, 0.f);
            *(ushort4*)(out + n * FOUT + q * 4) =
                make_ushort4(f2bf(ox), f2bf(oy), f2bf(oz), f2bf(ow));
        }
    }
}

// conv3 gather (R11 body, best measured): thread = (node, 4 feats of 80);
// 4-edge unroll, 2 chains, ushort4 loads; OUTPUT bf16 into padded rows
// (stride KS=96; pads pre-zeroed by memset).
template<int F, int KS>
__global__ void gather_bf16_kernel(const int* __restrict__ offs,
                                   const int2* __restrict__ perm,
                                   const ushort* __restrict__ H,
                                   const float* __restrict__ dinv,
                                   ushort* __restrict__ agg, int N) {
    constexpr int TPN = F / 4;
    int idx = blockIdx.x * blockDim.x + threadIdx.x;
    int node = idx / TPN, q = idx % TPN;
    if (node >= N) return;
    int s = offs[node], e = offs[node + 1];
    float4 a0 = make_float4(0.f, 0.f, 0.f, 0.f);
    float4 a1 = make_float4(0.f, 0.f, 0.f, 0.f);
    int j = s;
    for (; j + 4 <= e; j += 4) {
        int2 p0 = perm[j + 0], p1 = perm[j + 1], p2 = perm[j + 2], p3 = perm[j + 3];
        ushort4 u0 = *(const ushort4*)(H + (long)p0.x * F + q * 4);
        ushort4 u1 = *(const ushort4*)(H + (long)p1.x * F + q * 4);
        ushort4 u2 = *(const ushort4*)(H + (long)p2.x * F + q * 4);
        ushort4 u3 = *(const ushort4*)(H + (long)p3.x * F + q * 4);
        ACC4(a0, u0, __int_as_float(p0.y));
        ACC4(a1, u1, __int_as_float(p1.y));
        ACC4(a0, u2, __int_as_float(p2.y));
        ACC4(a1, u3, __int_as_float(p3.y));
    }
    for (; j < e; ++j) {
        int2 p = perm[j];
        ushort4 u = *(const ushort4*)(H + (long)p.x * F + q * 4);
        ACC4(a0, u, __int_as_float(p.y));
    }
    float di = dinv[node], d2 = di * di;
    ushort4 su = *(const ushort4*)(H + (long)node * F + q * 4);
    ACC4(a0, su, d2);
    a0.x += a1.x; a0.y += a1.y; a0.z += a1.z; a0.w += a1.w;
    *(ushort4*)(agg + (long)node * KS + q * 4) =
        make_ushort4(f2bf(a0.x), f2bf(a0.y), f2bf(a0.z), f2bf(a0.w));
}

// conv3 MFMA gemm + pool: uniform coalesced copy of NPB=64 agg rows (bf16,
// stride KS=96) into LDS -> 24x v_mfma_f32_16x16x32_bf16 per wave (R24
// layout, HW-verified) -> relu + hierarchical max-pool. No degree variance
// before the barrier -> no convoy. Copy = 12288B = 768 uint4 = 3/thread.
template<int FOUT, int NPB, int BLK>   // 128, 64, 256
__global__ __launch_bounds__(BLK)
void conv3_mfma_pool_kernel(const ushort* __restrict__ aggB,
                            const ushort* __restrict__ W3p,
                            const float* __restrict__ bias,
                            const int* __restrict__ batch,
                            unsigned int* __restrict__ g, int N) {
    constexpr int KS = 96;
    static_assert(NPB == 64 && BLK == 256 && FOUT == 128, "mfma tiling");
    __shared__ ushort aggs[NPB * KS];      // 12KB
    __shared__ unsigned int gma[2 * FOUT];
    __shared__ int sb[NPB];
    __shared__ int gfirst;
    int bb = blockIdx.x * NPB;
    int tid = (int)threadIdx.x;
    if (tid == 0) gfirst = batch[min(bb, N - 1)];
    if (tid < NPB) sb[tid] = batch[min(bb + tid, N - 1)];
    for (int i = tid; i < 2 * FOUT; i += BLK) gma[i] = 0u;
    // uniform copy: 64*96 ushorts = 12288B = 768 uint4 (16B), 3 per thread
    {
        const uint4* src = (const uint4*)(aggB + (size_t)bb * KS);
        uint4* dst = (uint4*)aggs;
#pragma unroll
        for (int i = 0; i < 3; ++i) dst[tid + i * BLK] = src[tid + i * BLK];
    }
    __syncthreads();

    // ---- MFMA gemm + pool ----
    int lane = tid & 63, w = tid >> 6;     // 4 waves, 16 rows each
    int la = lane & 15, kg = lane >> 4;
    f32x4 acc[8];
#pragma unroll
    for (int t = 0; t < 8; ++t) acc[t] = (f32x4){0.f, 0.f, 0.f, 0.f};
#pragma unroll
    for (int c = 0; c < 3; ++c) {
        bf16x8 a = *(const bf16x8*)&aggs[(w * 16 + la) * KS + c * 32 + kg * 8];
        const ushort* bp = W3p + (size_t)c * 4096 + la * 32 + kg * 8;
#pragma unroll
        for (int t = 0; t < 8; ++t) {
            bf16x8 b = *(const bf16x8*)(bp + t * 512);
            acc[t] = __builtin_amdgcn_mfma_f32_16x16x32_bf16(a, b, acc[t], 0, 0, 0);
        }
    }
    // C/D: col = t*16 + (lane&15), row = w*16 + (lane>>4)*4 + r
    int rowg = w * 16 + kg * 4;
#pragma unroll
    for (int t = 0; t < 8; ++t) {
        int colv = t * 16 + la;
        float bvv = bias[colv];
#pragma unroll
        for (int r = 0; r < 4; ++r) {
            int nl = rowg + r;
            long node = (long)bb + nl;
            if (node < N) {
                float v = fmaxf(acc[t][r] + bvv, 0.f);
                unsigned int uv = __float_as_uint(v);
                int bn = sb[nl];
                int rel = bn - gfirst;
                if (rel < 2) atomicMax(&gma[rel * FOUT + colv], uv);
                else atomicMax(&g[(long)bn * FOUT + colv], uv);
            }
        }
    }
    __syncthreads();
    for (int i = tid; i < 2 * FOUT; i += BLK) {
        unsigned int v = gma[i];
        if (v) atomicMax(&g[(long)(gfirst + i / FOUT) * FOUT + (i % FOUT)], v);
    }
}

// one block per graph: relu(g@Wfc1+bfc1) @ Wfc2 + bfc2 -> softmax
__global__ void fc_kernel(const float* __restrict__ g, const float* __restrict__ Wfc1,
                          const float* __restrict__ bfc1, const float* __restrict__ Wfc2,
                          const float* __restrict__ bfc2, float* __restrict__ out) {
    __shared__ float gs[128];
    __shared__ float red0[256], red1[256];
    int b = blockIdx.x, tid = threadIdx.x;
    if (tid < 128) gs[tid] = g[b * 128 + tid];
    __syncthreads();
    float h0 = bfc1[tid], h1 = bfc1[tid + 256];
    for (int k = 0; k < 128; ++k) {
        float gv = gs[k];
        h0 += gv * Wfc1[k * 512 + tid];
        h1 += gv * Wfc1[k * 512 + tid + 256];
    }
    h0 = fmaxf(h0, 0.f); h1 = fmaxf(h1, 0.f);
    red0[tid] = h0 * Wfc2[tid * 2 + 0] + h1 * Wfc2[(tid + 256) * 2 + 0];
    red1[tid] = h0 * Wfc2[tid * 2 + 1] + h1 * Wfc2[(tid + 256) * 2 + 1];
    __syncthreads();
    for (int s = 128; s > 0; s >>= 1) {
        if (tid < s) { red0[tid] += red0[tid + s]; red1[tid] += red1[tid + s]; }
        __syncthreads();
    }
    if (tid == 0) {
        float L0 = red0[0] + bfc2[0], L1 = red1[0] + bfc2[1];
        float m = fmaxf(L0, L1);
        float e0 = expf(L0 - m), e1 = expf(L1 - m);
        float inv = 1.f / (e0 + e1);
        out[b * 2 + 0] = e0 * inv;
        out[b * 2 + 1] = e1 * inv;
    }
}

extern "C" void kernel_launch(void* const* d_in, const int* in_sizes, int n_in,
                              void* d_out, int out_size, void* d_ws, size_t ws_size,
                              hipStream_t stream) {
    const float* x     = (const float*)d_in[0];
    const int*   ei    = (const int*)d_in[1];
    const float* ew    = (const float*)d_in[2];
    const int*   batch = (const int*)d_in[3];
    const float* W1    = (const float*)d_in[4];
    const float* b1    = (const float*)d_in[5];
    const float* W2    = (const float*)d_in[6];
    const float* b2    = (const float*)d_in[7];
    const float* W3    = (const float*)d_in[8];
    const float* b3    = (const float*)d_in[9];
    const float* Wfc1  = (const float*)d_in[10];
    const float* bfc1  = (const float*)d_in[11];
    const float* Wfc2  = (const float*)d_in[12];
    const float* bfc2  = (const float*)d_in[13];

    const int N = in_sizes[3];      // 100000
    const int E = in_sizes[2];      // 1600000
    const int* row = ei;
    const int* col = ei + E;

    char* ws = (char*)d_ws;
    float* dinv   = (float*)ws;              ws += align256((size_t)N * 4);
    int*   offs   = (int*)ws;                ws += align256((size_t)(N + 1) * 4);
    int*   bsums  = (int*)ws;                ws += align256((size_t)1024 * 4);
    int2*  perm   = (int2*)ws;               ws += align256((size_t)E * 8);
    float* bufA   = (float*)ws;              ws += align256((size_t)N * 128 * 4);  // build transients / aggB
    ushort* bufH1 = (ushort*)ws;             ws += align256((size_t)N * 40 * 2);   // H1 bf16
    ushort* bufH2 = (ushort*)ws;             ws += align256((size_t)N * 80 * 2);   // H2 bf16
    ushort* xbf   = (ushort*)ws;             ws += align256((size_t)N * 40 * 2);   // x bf16
    float* g      = (float*)ws;              ws += align256((size_t)512 * 128 * 4);
    ushort* W3p   = (ushort*)ws;             ws += align256((size_t)3 * 128 * 32 * 2);

    const int NB   = cdiv(N, 64);            // 1563 buckets (<= MAXNB)
    const int TOT  = NB * TB;                // (bucket, tile) cells = 400128
    const int chunkE = cdiv(E, TB);          // edges per tile = 6250
    const int nScanH = cdiv(TOT, SCHUNK);    // 391 (<= 1024)
    const int N64  = NB * 64;                // N rounded up to 64 (100032)

    // transients aliased into bufA (51.2MB; all dead before convs):
    // semi int2 (12.8MB) | gHist u32[TOT] (1.6MB) | scanned u32[TOT] (1.6MB)
    // later: aggB ushort[N64*96] (19.2MB) for conv3 split
    int2* semi = (int2*)bufA;
    unsigned int* gHist =
        (unsigned int*)((char*)bufA + align256((size_t)E * 8));
    unsigned int* scanned =
        (unsigned int*)((char*)gHist + align256((size_t)TOT * 4));
    ushort* aggB = (ushort*)bufA;

    const int B = 256;

    // --- atomic-free CSR build ---
    histA_kernel<<<TB, 512, 0, stream>>>(col, gHist, E, NB, chunkE,
                                         x, xbf, (long)N * 10);
    scanAH_kernel<<<nScanH, B, 0, stream>>>(gHist, bsums, TOT, NB);
    scanB_kernel<<<1, 1024, 0, stream>>>(bsums, offs, nScanH, N);
    scanCH_kernel<<<nScanH, B, 0, stream>>>(gHist, bsums, scanned, TOT, NB);
    scatterC_kernel<<<TB, 512, 0, stream>>>(row, col, ew, scanned, semi, E, NB, chunkE);
    fineD_kernel<<<NB, 256, 0, stream>>>(semi, scanned, offs, dinv, perm, E, N, NB);
    normE_kernel<<<cdiv(N, B), B, 0, stream>>>(offs, dinv, perm, N);
    w3prep_kernel<<<48, 256, 0, stream>>>(W3, W3p);

    // --- conv1 fused: H1 = relu((A*x)@W1 + b1) -> bufH1 (bf16) ---
    fused_conv_kernel<40, 40, 128, 320><<<cdiv(N, 128), 320, 0, stream>>>(
        offs, perm, xbf, dinv, W1, b1, bufH1, N);

    // --- conv2 fused: H2 = relu((A*H1)@W2 + b2) -> bufH2 (bf16) ---
    fused_conv_kernel<40, 80, 64, 320><<<cdiv(N, 64), 320, 0, stream>>>(
        offs, perm, bufH1, dinv, W2, b2, bufH2, N);

    // --- conv3 split: gather bf16 agg -> MFMA gemm + pool ---
    hipMemsetAsync(aggB, 0, (size_t)N64 * 96 * 2, stream);   // zero pads + tail
    gather_bf16_kernel<80, 96><<<cdiv((long)N * 20, B), B, 0, stream>>>(
        offs, perm, bufH2, dinv, aggB, N);
    hipMemsetAsync(g, 0, (size_t)512 * 128 * 4, stream);
    conv3_mfma_pool_kernel<128, 64, 256><<<NB, 256, 0, stream>>>(
        aggB, W3p, b3, batch, (unsigned int*)g, N);

    // --- MLP + softmax ---
    fc_kernel<<<512, 256, 0, stream>>>(g, Wfc1, bfc1, Wfc2, bfc2, (float*)d_out);
}

// Round 19
// 344.920 us; speedup vs baseline: 9.3226x; 1.0170x over previous
//
#include <hip/hip_runtime.h>

// ---------------------------------------------------------------------------
// GCNnet: 3x GCNConv (40->40->80->128) + global max pool + MLP(128->512->2) + softmax
// N=100000 nodes, E=1600000 edges, G=512 graphs.
// Round 27: R26 confirmed the convoy mechanism scales with GATHER ROUNDS per
// thread (conv3: 5 rounds fused = 80us vs 1 round standalone = 56us).
// conv1+conv2 (est. ~175us combined) run 4 and 2 rounds -> set NPB=32 for
// both: exactly 320 slots = 1 round/thread. Phase-2 re-tiles (NPT=1 / NPT=2);
// LDS shrinks (29->12KB, 24->18KB) -> more blocks/CU, more drift.
// Kernel bodies unchanged (proven); only template geometry.
// ---------------------------------------------------------------------------

static inline int cdiv(long a, int b) { return (int)((a + b - 1) / b); }
static inline size_t align256(size_t x) { return (x + 255) & ~(size_t)255; }

#define FXSCALE 16777216.0f           // 2^24
#define SCHUNK  1024                  // elements per scan block
#define BKT_SHIFT 6                   // 64 nodes per bucket
#define MAXNB   2048                  // LDS histogram capacity (N <= 131072)
#define TB      256                   // histogram tiles

typedef __attribute__((ext_vector_type(8))) short bf16x8;
typedef __attribute__((ext_vector_type(4))) float f32x4;

__device__ __forceinline__ float bf2f(unsigned short u) {
    return __uint_as_float(((unsigned int)u) << 16);
}
__device__ __forceinline__ unsigned short f2bf(float f) {   // round-nearest-even
    unsigned int u = __float_as_uint(f);
    return (unsigned short)((u + 0x7FFFu + ((u >> 16) & 1u)) >> 16);
}

#define ACC4(A, U, M)                                                         \
    do {                                                                      \
        A.x += bf2f((U).x) * (M); A.y += bf2f((U).y) * (M);                   \
        A.z += bf2f((U).z) * (M); A.w += bf2f((U).w) * (M);                   \
    } while (0)

// Pass A: per-tile LDS histogram over NB buckets (bucket = col>>6).
// gHist[tile][bucket]. Fused: x f32 -> bf16 (unpadded rows, stride 40).
__global__ __launch_bounds__(512)
void histA_kernel(const int* __restrict__ col, unsigned int* __restrict__ gHist,
                  int E, int NB, int chunk,
                  const float* __restrict__ x, ushort* __restrict__ xbf, long n4) {
    __shared__ unsigned int hist[MAXNB];
    int t = blockIdx.x;
    for (int i = threadIdx.x; i < NB; i += 512) hist[i] = 0u;
    __syncthreads();
    int s = t * chunk, e = min(s + chunk, E);
    for (int i = s + threadIdx.x; i < e; i += 512)
        atomicAdd(&hist[(unsigned int)col[i] >> BKT_SHIFT], 1u);
    // fused f2bf: i/10 = row, i%10 = float4 slot -> xbf[row*40 + slot*4]
    long gid = (long)t * 512 + threadIdx.x, gstride = (long)TB * 512;
    for (long i = gid; i < n4; i += gstride) {
        float4 v = ((const float4*)x)[i];
        long r = i / 10, c = i % 10;
        *(ushort4*)(xbf + r * 40 + c * 4) =
            make_ushort4(f2bf(v.x), f2bf(v.y), f2bf(v.z), f2bf(v.w));
    }
    __syncthreads();
    for (int b = threadIdx.x; b < NB; b += 512)
        gHist[(size_t)t * NB + b] = hist[b];
}

// scan phase A (histogram variant): per-block sums of the bucket-major view
// element i -> gHist[(i&255)*NB + (i>>8)]   (i = bucket*256 + tile)
__global__ void scanAH_kernel(const unsigned int* __restrict__ gHist,
                              int* __restrict__ blockSums, int TOT, int NB) {
    __shared__ int wred[4];
    int tid = threadIdx.x, lane = tid & 63, wid = tid >> 6;
    int i0 = blockIdx.x * SCHUNK + tid * 4;
    int s = 0;
#pragma unroll
    for (int k = 0; k < 4; ++k) {
        int i = i0 + k;
        if (i < TOT) s += (int)gHist[(size_t)(i & 255) * NB + (i >> 8)];
    }
#pragma unroll
    for (int off = 32; off > 0; off >>= 1) s += __shfl_down(s, off, 64);
    if (lane == 0) wred[wid] = s;
    __syncthreads();
    if (tid == 0) blockSums[blockIdx.x] = wred[0] + wred[1] + wred[2] + wred[3];
}

// scan phase B: one block, exclusive scan of blockSums[nb] (nb <= 1024);
// writes grand total into offs[N] (= E).
__global__ void scanB_kernel(int* __restrict__ blockSums, int* __restrict__ offs,
                             int nb, int N) {
    __shared__ int wsum[16];
    int tid = threadIdx.x, lane = tid & 63, wid = tid >> 6;
    int v = (tid < nb) ? blockSums[tid] : 0;
    int incl = v;
#pragma unroll
    for (int off = 1; off < 64; off <<= 1) {
        int t = __shfl_up(incl, off, 64);
        if (lane >= off) incl += t;
    }
    if (lane == 63) wsum[wid] = incl;
    __syncthreads();
    if (wid == 0 && lane < 16) {
        int w = wsum[lane];
        int ic = w;
#pragma unroll
        for (int off = 1; off < 16; off <<= 1) {
            int t = __shfl_up(ic, off, 64);
            if (lane >= off) ic += t;
        }
        wsum[lane] = ic - w;   // exclusive
    }
    __syncthreads();
    if (tid < nb) blockSums[tid] = wsum[wid] + incl - v;   // exclusive prefix
    if (tid == 1023) offs[N] = wsum[15] + incl;            // grand total
}

// scan phase C (histogram variant): local exclusive scan + block offset ->
// scanned[i] = global output cursor for (bucket = i>>8, tile = i&255)
__global__ void scanCH_kernel(const unsigned int* __restrict__ gHist,
                              const int* __restrict__ blockSums,
                              unsigned int* __restrict__ scanned, int TOT, int NB) {
    __shared__ int wsum[4];
    int tid = threadIdx.x, lane = tid & 63, wid = tid >> 6;
    int i0 = blockIdx.x * SCHUNK + tid * 4;
    int v0 = 0, v1 = 0, v2 = 0, v3 = 0;
    if (i0 + 0 < TOT) v0 = (int)gHist[(size_t)((i0 + 0) & 255) * NB + ((i0 + 0) >> 8)];
    if (i0 + 1 < TOT) v1 = (int)gHist[(size_t)((i0 + 1) & 255) * NB + ((i0 + 1) >> 8)];
    if (i0 + 2 < TOT) v2 = (int)gHist[(size_t)((i0 + 2) & 255) * NB + ((i0 + 2) >> 8)];
    if (i0 + 3 < TOT) v3 = (int)gHist[(size_t)((i0 + 3) & 255) * NB + ((i0 + 3) >> 8)];
    int sum = v0 + v1 + v2 + v3;
    int incl = sum;
#pragma unroll
    for (int off = 1; off < 64; off <<= 1) {
        int t = __shfl_up(incl, off, 64);
        if (lane >= off) incl += t;
    }
    if (lane == 63) wsum[wid] = incl;
    __syncthreads();
    if (tid == 0) {
        int c = 0;
#pragma unroll
        for (int k = 0; k < 4; ++k) { int t = wsum[k]; wsum[k] = c; c += t; }
    }
    __syncthreads();
    int pre = blockSums[blockIdx.x] + wsum[wid] + (incl - sum);
    if (i0 + 0 < TOT) scanned[i0 + 0] = (unsigned int)pre;
    if (i0 + 1 < TOT) scanned[i0 + 1] = (unsigned int)(pre + v0);
    if (i0 + 2 < TOT) scanned[i0 + 2] = (unsigned int)(pre + v0 + v1);
    if (i0 + 3 < TOT) scanned[i0 + 3] = (unsigned int)(pre + v0 + v1 + v2);
}

// Pass C: scatter edges into bucket-grouped semi[] via LDS cursors.
// semi[pos] = {row | (col&63)<<17, wbits} (int2, row < 2^17).
__global__ __launch_bounds__(512)
void scatterC_kernel(const int* __restrict__ row, const int* __restrict__ col,
                     const float* __restrict__ w,
                     const unsigned int* __restrict__ scanned,
                     int2* __restrict__ semi, int E, int NB, int chunk) {
    __shared__ unsigned int cur[MAXNB];
    int t = blockIdx.x;
    for (int b = threadIdx.x; b < NB; b += 512)
        cur[b] = scanned[(size_t)b * TB + t];
    __syncthreads();
    int s = t * chunk, e = min(s + chunk, E);
    for (int i = s + threadIdx.x; i < e; i += 512) {
        int c = col[i];
        unsigned int pos = atomicAdd(&cur[(unsigned int)c >> BKT_SHIFT], 1u);
        semi[pos] = make_int2(row[i] | ((c & 63) << 17), __float_as_int(w[i]));
    }
}

// Pass D: one block per bucket (64 nodes). Fine counting sort by c6,
// per-node weighted degree (fixed-point LDS atomics) -> perm {row,wbits},
// offs, dinv. All atomics LDS.
__global__ __launch_bounds__(256)
void fineD_kernel(const int2* __restrict__ semi, const unsigned int* __restrict__ scanned,
                  int* __restrict__ offs, float* __restrict__ dinv,
                  int2* __restrict__ perm, int E, int N, int NB) {
    __shared__ unsigned int cnt[64], cur[64], wsum[64];
    __shared__ int nodeOffs[64];
    int b = blockIdx.x, tid = threadIdx.x;
    int s = (int)scanned[(size_t)b * TB];
    int e = (b + 1 < NB) ? (int)scanned[(size_t)(b + 1) * TB] : E;
    if (tid < 64) { cnt[tid] = 0u; wsum[tid] = 0u; }
    __syncthreads();
    for (int i = s + tid; i < e; i += 256) {
        int2 v = semi[i];
        int c6 = (v.x >> 17) & 63;
        atomicAdd(&cnt[c6], 1u);
        atomicAdd(&wsum[c6], (unsigned int)llrintf(__int_as_float(v.y) * FXSCALE));
    }
    __syncthreads();
    if (tid < 64) {
        int v = (int)cnt[tid];
        int incl = v;
#pragma unroll
        for (int off = 1; off < 64; off <<= 1) {
            int u = __shfl_up(incl, off, 64);
            if (tid >= off) incl += u;
        }
        nodeOffs[tid] = incl - v;          // exclusive within bucket
        cur[tid] = (unsigned int)(incl - v);
    }
    __syncthreads();
    for (int i = s + tid; i < e; i += 256) {
        int2 v = semi[i];
        int c6 = (v.x >> 17) & 63;
        unsigned int r = atomicAdd(&cur[c6], 1u);
        perm[s + (int)r] = make_int2(v.x & 0x1FFFF, v.y);   // {row, wbits}
    }
    if (tid < 64) {
        int node = (b << BKT_SHIFT) + tid;
        if (node < N) {
            offs[node] = s + nodeOffs[tid];
            float deg = (float)wsum[tid] * (1.0f / FXSCALE);
            dinv[node] = rsqrtf(deg + 1.0f);
        }
    }
    if (b == NB - 1 && tid == 0) offs[N] = E;
}

// Pass E: perm.y = dinv[row] * w * dinv[col]  (thread per destination node)
__global__ void normE_kernel(const int* __restrict__ offs, const float* __restrict__ dinv,
                             int2* __restrict__ perm, int N) {
    int n = blockIdx.x * blockDim.x + threadIdx.x;
    if (n >= N) return;
    int s = offs[n], e = offs[n + 1];
    float dc = dinv[n];
    for (int j = s; j < e; ++j) {
        int2 p = perm[j];
        float nm = dinv[p.x] * __int_as_float(p.y) * dc;
        perm[j] = make_int2(p.x, __float_as_int(nm));
    }
}

// W3 -> bf16 packed for MFMA B-fragments: W3p[(c*128+col)*32 + kk] =
// bf16(W3[c*32+kk][col]), zero for k >= 80. 3 chunks of K=32.
__global__ void w3prep_kernel(const float* __restrict__ W3, ushort* __restrict__ W3p) {
    int i = blockIdx.x * 256 + threadIdx.x;
    if (i >= 3 * 128 * 32) return;
    int kk = i & 31, c = i >> 12, colv = (i >> 5) & 127;
    int k = c * 32 + kk;
    float v = (k < 80) ? W3[k * 128 + colv] : 0.f;
    W3p[i] = f2bf(v);
}

// Fused conv (conv1/conv2): phase1 = R11 gather into LDS agg (rows padded to
// K+4 floats vs phase-2 bank conflicts); sync; phase2 = gemm from LDS, relu,
// bf16 out. NPB=32 -> exactly ONE gather round per thread (no round convoy).
template<int K, int FOUT, int NPB, int BLK>
__global__ __launch_bounds__(BLK)
void fused_conv_kernel(const int* __restrict__ offs, const int2* __restrict__ perm,
                       const ushort* __restrict__ H, const float* __restrict__ dinv,
                       const float* __restrict__ W, const float* __restrict__ bias,
                       ushort* __restrict__ out, int N) {
    constexpr int TPN = K / 4;
    constexpr int TPQ = FOUT / 4;
    constexpr int NPT = (NPB * TPQ) / BLK;   // nodes per phase-2 thread
    constexpr int KP = K + 4;              // padded agg row (floats)
    static_assert((NPB * TPN) % BLK == 0, "phase1 tiling");
    static_assert(NPT >= 1 && (NPB % NPT) == 0, "phase2 nodes");
    static_assert((NPB / NPT) * TPQ == BLK, "phase2 tiling");
    __shared__ float wsm[K * FOUT];
    __shared__ float aggs[NPB * KP];
    for (int i = threadIdx.x; i < K * FOUT; i += BLK) wsm[i] = W[i];

    // ---- phase 1: gather into LDS ----
#pragma unroll
    for (int p0 = 0; p0 < NPB * TPN; p0 += BLK) {
        int p = p0 + threadIdx.x;
        int nl = p / TPN, q = p % TPN;
        int node = blockIdx.x * NPB + nl;
        float4 a0 = make_float4(0.f, 0.f, 0.f, 0.f);
        float4 a1 = make_float4(0.f, 0.f, 0.f, 0.f);
        if (node < N) {
            int s = offs[node], e = offs[node + 1];
            int j = s;
            for (; j + 4 <= e; j += 4) {
                int2 p0e = perm[j + 0], p1e = perm[j + 1];
                int2 p2e = perm[j + 2], p3e = perm[j + 3];
                ushort4 u0 = *(const ushort4*)(H + (long)p0e.x * K + q * 4);
                ushort4 u1 = *(const ushort4*)(H + (long)p1e.x * K + q * 4);
                ushort4 u2 = *(const ushort4*)(H + (long)p2e.x * K + q * 4);
                ushort4 u3 = *(const ushort4*)(H + (long)p3e.x * K + q * 4);
                ACC4(a0, u0, __int_as_float(p0e.y));
                ACC4(a1, u1, __int_as_float(p1e.y));
                ACC4(a0, u2, __int_as_float(p2e.y));
                ACC4(a1, u3, __int_as_float(p3e.y));
            }
            for (; j < e; ++j) {
                int2 pe = perm[j];
                ushort4 u = *(const ushort4*)(H + (long)pe.x * K + q * 4);
                ACC4(a0, u, __int_as_float(pe.y));
            }
            float di = dinv[node], d2 = di * di;
            ushort4 su = *(const ushort4*)(H + (long)node * K + q * 4);
            ACC4(a0, su, d2);
        }
        a0.x += a1.x; a0.y += a1.y; a0.z += a1.z; a0.w += a1.w;
        *(float4*)&aggs[nl * KP + q * 4] = a0;
    }
    __syncthreads();

    // ---- phase 2: gemm from LDS ----
    int q = threadIdx.x % TPQ, pg = threadIdx.x / TPQ;
    long nbase = (long)blockIdx.x * NPB + (long)pg * NPT;
    float4 acc[NPT];
#pragma unroll
    for (int t = 0; t < NPT; ++t) acc[t] = make_float4(0.f, 0.f, 0.f, 0.f);
    const float* wq = wsm + q * 4;
#pragma unroll 4
    for (int i = 0; i < K / 4; ++i) {
        float4 xv[NPT];
#pragma unroll
        for (int t = 0; t < NPT; ++t)
            xv[t] = *(const float4*)&aggs[(pg * NPT + t) * KP + i * 4];
#pragma unroll
        for (int j = 0; j < 4; ++j) {
            float4 wv = *(const float4*)(wq + (i * 4 + j) * FOUT);
#pragma unroll
            for (int t = 0; t < NPT; ++t) {
                float v = ((const float*)&xv[t])[j];
                acc[t].x += v * wv.x; acc[t].y += v * wv.y;
                acc[t].z += v * wv.z; acc[t].w += v * wv.w;
            }
        }
    }
    float4 bv = *(const float4*)(bias + q * 4);
#pragma unroll
    for (int t = 0; t < NPT; ++t) {
        long n = nbase + t;
        if (n < N) {
            float ox = fmaxf(acc[t].x + bv.x, 0.f);
            float oy = fmaxf(acc[t].y + bv.y, 0.f);
            float oz = fmaxf(acc[t].z + bv.z, 0.f);
            float ow = fmaxf(acc[t].w + bv.w, 0.f);
            *(ushort4*)(out + n * FOUT + q * 4) =
                make_ushort4(f2bf(ox), f2bf(oy), f2bf(oz), f2bf(ow));
        }
    }
}

// conv3 gather (R11 body, best measured): thread = (node, 4 feats of 80);
// 4-edge unroll, 2 chains, ushort4 loads; OUTPUT bf16 into padded rows
// (stride KS=96; pads pre-zeroed by memset).
template<int F, int KS>
__global__ void gather_bf16_kernel(const int* __restrict__ offs,
                                   const int2* __restrict__ perm,
                                   const ushort* __restrict__ H,
                                   const float* __restrict__ dinv,
                                   ushort* __restrict__ agg, int N) {
    constexpr int TPN = F / 4;
    int idx = blockIdx.x * blockDim.x + threadIdx.x;
    int node = idx / TPN, q = idx % TPN;
    if (node >= N) return;
    int s = offs[node], e = offs[node + 1];
    float4 a0 = make_float4(0.f, 0.f, 0.f, 0.f);
    float4 a1 = make_float4(0.f, 0.f, 0.f, 0.f);
    int j = s;
    for (; j + 4 <= e; j += 4) {
        int2 p0 = perm[j + 0], p1 = perm[j + 1], p2 = perm[j + 2], p3 = perm[j + 3];
        ushort4 u0 = *(const ushort4*)(H + (long)p0.x * F + q * 4);
        ushort4 u1 = *(const ushort4*)(H + (long)p1.x * F + q * 4);
        ushort4 u2 = *(const ushort4*)(H + (long)p2.x * F + q * 4);
        ushort4 u3 = *(const ushort4*)(H + (long)p3.x * F + q * 4);
        ACC4(a0, u0, __int_as_float(p0.y));
        ACC4(a1, u1, __int_as_float(p1.y));
        ACC4(a0, u2, __int_as_float(p2.y));
        ACC4(a1, u3, __int_as_float(p3.y));
    }
    for (; j < e; ++j) {
        int2 p = perm[j];
        ushort4 u = *(const ushort4*)(H + (long)p.x * F + q * 4);
        ACC4(a0, u, __int_as_float(p.y));
    }
    float di = dinv[node], d2 = di * di;
    ushort4 su = *(const ushort4*)(H + (long)node * F + q * 4);
    ACC4(a0, su, d2);
    a0.x += a1.x; a0.y += a1.y; a0.z += a1.z; a0.w += a1.w;
    *(ushort4*)(agg + (long)node * KS + q * 4) =
        make_ushort4(f2bf(a0.x), f2bf(a0.y), f2bf(a0.z), f2bf(a0.w));
}

// conv3 MFMA gemm + pool: uniform coalesced copy of NPB=64 agg rows (bf16,
// stride KS=96) into LDS -> 24x v_mfma_f32_16x16x32_bf16 per wave (R24
// layout, HW-verified) -> relu + hierarchical max-pool. No degree variance
// before the barrier -> no convoy. Copy = 12288B = 768 uint4 = 3/thread.
template<int FOUT, int NPB, int BLK>   // 128, 64, 256
__global__ __launch_bounds__(BLK)
void conv3_mfma_pool_kernel(const ushort* __restrict__ aggB,
                            const ushort* __restrict__ W3p,
                            const float* __restrict__ bias,
                            const int* __restrict__ batch,
                            unsigned int* __restrict__ g, int N) {
    constexpr int KS = 96;
    static_assert(NPB == 64 && BLK == 256 && FOUT == 128, "mfma tiling");
    __shared__ ushort aggs[NPB * KS];      // 12KB
    __shared__ unsigned int gma[2 * FOUT];
    __shared__ int sb[NPB];
    __shared__ int gfirst;
    int bb = blockIdx.x * NPB;
    int tid = (int)threadIdx.x;
    if (tid == 0) gfirst = batch[min(bb, N - 1)];
    if (tid < NPB) sb[tid] = batch[min(bb + tid, N - 1)];
    for (int i = tid; i < 2 * FOUT; i += BLK) gma[i] = 0u;
    // uniform copy: 64*96 ushorts = 12288B = 768 uint4 (16B), 3 per thread
    {
        const uint4* src = (const uint4*)(aggB + (size_t)bb * KS);
        uint4* dst = (uint4*)aggs;
#pragma unroll
        for (int i = 0; i < 3; ++i) dst[tid + i * BLK] = src[tid + i * BLK];
    }
    __syncthreads();

    // ---- MFMA gemm + pool ----
    int lane = tid & 63, w = tid >> 6;     // 4 waves, 16 rows each
    int la = lane & 15, kg = lane >> 4;
    f32x4 acc[8];
#pragma unroll
    for (int t = 0; t < 8; ++t) acc[t] = (f32x4){0.f, 0.f, 0.f, 0.f};
#pragma unroll
    for (int c = 0; c < 3; ++c) {
        bf16x8 a = *(const bf16x8*)&aggs[(w * 16 + la) * KS + c * 32 + kg * 8];
        const ushort* bp = W3p + (size_t)c * 4096 + la * 32 + kg * 8;
#pragma unroll
        for (int t = 0; t < 8; ++t) {
            bf16x8 b = *(const bf16x8*)(bp + t * 512);
            acc[t] = __builtin_amdgcn_mfma_f32_16x16x32_bf16(a, b, acc[t], 0, 0, 0);
        }
    }
    // C/D: col = t*16 + (lane&15), row = w*16 + (lane>>4)*4 + r
    int rowg = w * 16 + kg * 4;
#pragma unroll
    for (int t = 0; t < 8; ++t) {
        int colv = t * 16 + la;
        float bvv = bias[colv];
#pragma unroll
        for (int r = 0; r < 4; ++r) {
            int nl = rowg + r;
            long node = (long)bb + nl;
            if (node < N) {
                float v = fmaxf(acc[t][r] + bvv, 0.f);
                unsigned int uv = __float_as_uint(v);
                int bn = sb[nl];
                int rel = bn - gfirst;
                if (rel < 2) atomicMax(&gma[rel * FOUT + colv], uv);
                else atomicMax(&g[(long)bn * FOUT + colv], uv);
            }
        }
    }
    __syncthreads();
    for (int i = tid; i < 2 * FOUT; i += BLK) {
        unsigned int v = gma[i];
        if (v) atomicMax(&g[(long)(gfirst + i / FOUT) * FOUT + (i % FOUT)], v);
    }
}

// one block per graph: relu(g@Wfc1+bfc1) @ Wfc2 + bfc2 -> softmax
__global__ void fc_kernel(const float* __restrict__ g, const float* __restrict__ Wfc1,
                          const float* __restrict__ bfc1, const float* __restrict__ Wfc2,
                          const float* __restrict__ bfc2, float* __restrict__ out) {
    __shared__ float gs[128];
    __shared__ float red0[256], red1[256];
    int b = blockIdx.x, tid = threadIdx.x;
    if (tid < 128) gs[tid] = g[b * 128 + tid];
    __syncthreads();
    float h0 = bfc1[tid], h1 = bfc1[tid + 256];
    for (int k = 0; k < 128; ++k) {
        float gv = gs[k];
        h0 += gv * Wfc1[k * 512 + tid];
        h1 += gv * Wfc1[k * 512 + tid + 256];
    }
    h0 = fmaxf(h0, 0.f); h1 = fmaxf(h1, 0.f);
    red0[tid] = h0 * Wfc2[tid * 2 + 0] + h1 * Wfc2[(tid + 256) * 2 + 0];
    red1[tid] = h0 * Wfc2[tid * 2 + 1] + h1 * Wfc2[(tid + 256) * 2 + 1];
    __syncthreads();
    for (int s = 128; s > 0; s >>= 1) {
        if (tid < s) { red0[tid] += red0[tid + s]; red1[tid] += red1[tid + s]; }
        __syncthreads();
    }
    if (tid == 0) {
        float L0 = red0[0] + bfc2[0], L1 = red1[0] + bfc2[1];
        float m = fmaxf(L0, L1);
        float e0 = expf(L0 - m), e1 = expf(L1 - m);
        float inv = 1.f / (e0 + e1);
        out[b * 2 + 0] = e0 * inv;
        out[b * 2 + 1] = e1 * inv;
    }
}

extern "C" void kernel_launch(void* const* d_in, const int* in_sizes, int n_in,
                              void* d_out, int out_size, void* d_ws, size_t ws_size,
                              hipStream_t stream) {
    const float* x     = (const float*)d_in[0];
    const int*   ei    = (const int*)d_in[1];
    const float* ew    = (const float*)d_in[2];
    const int*   batch = (const int*)d_in[3];
    const float* W1    = (const float*)d_in[4];
    const float* b1    = (const float*)d_in[5];
    const float* W2    = (const float*)d_in[6];
    const float* b2    = (const float*)d_in[7];
    const float* W3    = (const float*)d_in[8];
    const float* b3    = (const float*)d_in[9];
    const float* Wfc1  = (const float*)d_in[10];
    const float* bfc1  = (const float*)d_in[11];
    const float* Wfc2  = (const float*)d_in[12];
    const float* bfc2  = (const float*)d_in[13];

    const int N = in_sizes[3];      // 100000
    const int E = in_sizes[2];      // 1600000
    const int* row = ei;
    const int* col = ei + E;

    char* ws = (char*)d_ws;
    float* dinv   = (float*)ws;              ws += align256((size_t)N * 4);
    int*   offs   = (int*)ws;                ws += align256((size_t)(N + 1) * 4);
    int*   bsums  = (int*)ws;                ws += align256((size_t)1024 * 4);
    int2*  perm   = (int2*)ws;               ws += align256((size_t)E * 8);
    float* bufA   = (float*)ws;              ws += align256((size_t)N * 128 * 4);  // build transients / aggB
    ushort* bufH1 = (ushort*)ws;             ws += align256((size_t)N * 40 * 2);   // H1 bf16
    ushort* bufH2 = (ushort*)ws;             ws += align256((size_t)N * 80 * 2);   // H2 bf16
    ushort* xbf   = (ushort*)ws;             ws += align256((size_t)N * 40 * 2);   // x bf16
    float* g      = (float*)ws;              ws += align256((size_t)512 * 128 * 4);
    ushort* W3p   = (ushort*)ws;             ws += align256((size_t)3 * 128 * 32 * 2);

    const int NB   = cdiv(N, 64);            // 1563 buckets (<= MAXNB)
    const int TOT  = NB * TB;                // (bucket, tile) cells = 400128
    const int chunkE = cdiv(E, TB);          // edges per tile = 6250
    const int nScanH = cdiv(TOT, SCHUNK);    // 391 (<= 1024)
    const int N64  = NB * 64;                // N rounded up to 64 (100032)

    // transients aliased into bufA (51.2MB; all dead before convs):
    // semi int2 (12.8MB) | gHist u32[TOT] (1.6MB) | scanned u32[TOT] (1.6MB)
    // later: aggB ushort[N64*96] (19.2MB) for conv3 split
    int2* semi = (int2*)bufA;
    unsigned int* gHist =
        (unsigned int*)((char*)bufA + align256((size_t)E * 8));
    unsigned int* scanned =
        (unsigned int*)((char*)gHist + align256((size_t)TOT * 4));
    ushort* aggB = (ushort*)bufA;

    const int B = 256;

    // --- atomic-free CSR build ---
    histA_kernel<<<TB, 512, 0, stream>>>(col, gHist, E, NB, chunkE,
                                         x, xbf, (long)N * 10);
    scanAH_kernel<<<nScanH, B, 0, stream>>>(gHist, bsums, TOT, NB);
    scanB_kernel<<<1, 1024, 0, stream>>>(bsums, offs, nScanH, N);
    scanCH_kernel<<<nScanH, B, 0, stream>>>(gHist, bsums, scanned, TOT, NB);
    scatterC_kernel<<<TB, 512, 0, stream>>>(row, col, ew, scanned, semi, E, NB, chunkE);
    fineD_kernel<<<NB, 256, 0, stream>>>(semi, scanned, offs, dinv, perm, E, N, NB);
    normE_kernel<<<cdiv(N, B), B, 0, stream>>>(offs, dinv, perm, N);
    w3prep_kernel<<<48, 256, 0, stream>>>(W3, W3p);

    // --- conv1 fused (1 gather round): H1 = relu((A*x)@W1 + b1) -> bufH1 ---
    fused_conv_kernel<40, 40, 32, 320><<<cdiv(N, 32), 320, 0, stream>>>(
        offs, perm, xbf, dinv, W1, b1, bufH1, N);

    // --- conv2 fused (1 gather round): H2 = relu((A*H1)@W2 + b2) -> bufH2 ---
    fused_conv_kernel<40, 80, 32, 320><<<cdiv(N, 32), 320, 0, stream>>>(
        offs, perm, bufH1, dinv, W2, b2, bufH2, N);

    // --- conv3 split: gather bf16 agg -> MFMA gemm + pool ---
    hipMemsetAsync(aggB, 0, (size_t)N64 * 96 * 2, stream);   // zero pads + tail
    gather_bf16_kernel<80, 96><<<cdiv((long)N * 20, B), B, 0, stream>>>(
        offs, perm, bufH2, dinv, aggB, N);
    hipMemsetAsync(g, 0, (size_t)512 * 128 * 4, stream);
    conv3_mfma_pool_kernel<128, 64, 256><<<NB, 256, 0, stream>>>(
        aggB, W3p, b3, batch, (unsigned int*)g, N);

    // --- MLP + softmax ---
    fc_kernel<<<512, 256, 0, stream>>>(g, Wfc1, bfc1, Wfc2, bfc2, (float*)d_out);
}

// Round 20
// 326.325 us; speedup vs baseline: 9.8538x; 1.0570x over previous
//
#include <hip/hip_runtime.h>

// ---------------------------------------------------------------------------
// GCNnet: 3x GCNConv (40->40->80->128) + global max pool + MLP(128->512->2) + softmax
// N=100000 nodes, E=1600000 edges, G=512 graphs.
// Round 28: gathers are at their collective random-access fabric bound
// (512MB @ ~3.6TB/s = ~140us, measured ~140us). Remaining quantified waste:
// (a) 19.2MB aggB memset -> fold pad-zeroing into gather_bf16 (q<4 writes
//     one zero ushort4; tail rows >=N garbage but discarded at pool guard);
// (b) normE's 26MB perm round-trip -> split fineD into D1 (cnt/wsum ->
//     offs,dinv; semi read 1) + D2 (scatter with NORM FUSED, cursors seeded
//     from offs; semi read 2). Same semi traffic, normE eliminated.
// Everything else = R27 (344.9us).
// ---------------------------------------------------------------------------

static inline int cdiv(long a, int b) { return (int)((a + b - 1) / b); }
static inline size_t align256(size_t x) { return (x + 255) & ~(size_t)255; }

#define FXSCALE 16777216.0f           // 2^24
#define SCHUNK  1024                  // elements per scan block
#define BKT_SHIFT 6                   // 64 nodes per bucket
#define MAXNB   2048                  // LDS histogram capacity (N <= 131072)
#define TB      256                   // histogram tiles

typedef __attribute__((ext_vector_type(8))) short bf16x8;
typedef __attribute__((ext_vector_type(4))) float f32x4;

__device__ __forceinline__ float bf2f(unsigned short u) {
    return __uint_as_float(((unsigned int)u) << 16);
}
__device__ __forceinline__ unsigned short f2bf(float f) {   // round-nearest-even
    unsigned int u = __float_as_uint(f);
    return (unsigned short)((u + 0x7FFFu + ((u >> 16) & 1u)) >> 16);
}

#define ACC4(A, U, M)                                                         \
    do {                                                                      \
        A.x += bf2f((U).x) * (M); A.y += bf2f((U).y) * (M);                   \
        A.z += bf2f((U).z) * (M); A.w += bf2f((U).w) * (M);                   \
    } while (0)

// Pass A: per-tile LDS histogram over NB buckets (bucket = col>>6).
// gHist[tile][bucket]. Fused: x f32 -> bf16 (unpadded rows, stride 40).
__global__ __launch_bounds__(512)
void histA_kernel(const int* __restrict__ col, unsigned int* __restrict__ gHist,
                  int E, int NB, int chunk,
                  const float* __restrict__ x, ushort* __restrict__ xbf, long n4) {
    __shared__ unsigned int hist[MAXNB];
    int t = blockIdx.x;
    for (int i = threadIdx.x; i < NB; i += 512) hist[i] = 0u;
    __syncthreads();
    int s = t * chunk, e = min(s + chunk, E);
    for (int i = s + threadIdx.x; i < e; i += 512)
        atomicAdd(&hist[(unsigned int)col[i] >> BKT_SHIFT], 1u);
    // fused f2bf: i/10 = row, i%10 = float4 slot -> xbf[row*40 + slot*4]
    long gid = (long)t * 512 + threadIdx.x, gstride = (long)TB * 512;
    for (long i = gid; i < n4; i += gstride) {
        float4 v = ((const float4*)x)[i];
        long r = i / 10, c = i % 10;
        *(ushort4*)(xbf + r * 40 + c * 4) =
            make_ushort4(f2bf(v.x), f2bf(v.y), f2bf(v.z), f2bf(v.w));
    }
    __syncthreads();
    for (int b = threadIdx.x; b < NB; b += 512)
        gHist[(size_t)t * NB + b] = hist[b];
}

// scan phase A (histogram variant): per-block sums of the bucket-major view
// element i -> gHist[(i&255)*NB + (i>>8)]   (i = bucket*256 + tile)
__global__ void scanAH_kernel(const unsigned int* __restrict__ gHist,
                              int* __restrict__ blockSums, int TOT, int NB) {
    __shared__ int wred[4];
    int tid = threadIdx.x, lane = tid & 63, wid = tid >> 6;
    int i0 = blockIdx.x * SCHUNK + tid * 4;
    int s = 0;
#pragma unroll
    for (int k = 0; k < 4; ++k) {
        int i = i0 + k;
        if (i < TOT) s += (int)gHist[(size_t)(i & 255) * NB + (i >> 8)];
    }
#pragma unroll
    for (int off = 32; off > 0; off >>= 1) s += __shfl_down(s, off, 64);
    if (lane == 0) wred[wid] = s;
    __syncthreads();
    if (tid == 0) blockSums[blockIdx.x] = wred[0] + wred[1] + wred[2] + wred[3];
}

// scan phase B: one block, exclusive scan of blockSums[nb] (nb <= 1024);
// writes grand total into offs[N] (= E).
__global__ void scanB_kernel(int* __restrict__ blockSums, int* __restrict__ offs,
                             int nb, int N) {
    __shared__ int wsum[16];
    int tid = threadIdx.x, lane = tid & 63, wid = tid >> 6;
    int v = (tid < nb) ? blockSums[tid] : 0;
    int incl = v;
#pragma unroll
    for (int off = 1; off < 64; off <<= 1) {
        int t = __shfl_up(incl, off, 64);
        if (lane >= off) incl += t;
    }
    if (lane == 63) wsum[wid] = incl;
    __syncthreads();
    if (wid == 0 && lane < 16) {
        int w = wsum[lane];
        int ic = w;
#pragma unroll
        for (int off = 1; off < 16; off <<= 1) {
            int t = __shfl_up(ic, off, 64);
            if (lane >= off) ic += t;
        }
        wsum[lane] = ic - w;   // exclusive
    }
    __syncthreads();
    if (tid < nb) blockSums[tid] = wsum[wid] + incl - v;   // exclusive prefix
    if (tid == 1023) offs[N] = wsum[15] + incl;            // grand total
}

// scan phase C (histogram variant): local exclusive scan + block offset ->
// scanned[i] = global output cursor for (bucket = i>>8, tile = i&255)
__global__ void scanCH_kernel(const unsigned int* __restrict__ gHist,
                              const int* __restrict__ blockSums,
                              unsigned int* __restrict__ scanned, int TOT, int NB) {
    __shared__ int wsum[4];
    int tid = threadIdx.x, lane = tid & 63, wid = tid >> 6;
    int i0 = blockIdx.x * SCHUNK + tid * 4;
    int v0 = 0, v1 = 0, v2 = 0, v3 = 0;
    if (i0 + 0 < TOT) v0 = (int)gHist[(size_t)((i0 + 0) & 255) * NB + ((i0 + 0) >> 8)];
    if (i0 + 1 < TOT) v1 = (int)gHist[(size_t)((i0 + 1) & 255) * NB + ((i0 + 1) >> 8)];
    if (i0 + 2 < TOT) v2 = (int)gHist[(size_t)((i0 + 2) & 255) * NB + ((i0 + 2) >> 8)];
    if (i0 + 3 < TOT) v3 = (int)gHist[(size_t)((i0 + 3) & 255) * NB + ((i0 + 3) >> 8)];
    int sum = v0 + v1 + v2 + v3;
    int incl = sum;
#pragma unroll
    for (int off = 1; off < 64; off <<= 1) {
        int t = __shfl_up(incl, off, 64);
        if (lane >= off) incl += t;
    }
    if (lane == 63) wsum[wid] = incl;
    __syncthreads();
    if (tid == 0) {
        int c = 0;
#pragma unroll
        for (int k = 0; k < 4; ++k) { int t = wsum[k]; wsum[k] = c; c += t; }
    }
    __syncthreads();
    int pre = blockSums[blockIdx.x] + wsum[wid] + (incl - sum);
    if (i0 + 0 < TOT) scanned[i0 + 0] = (unsigned int)pre;
    if (i0 + 1 < TOT) scanned[i0 + 1] = (unsigned int)(pre + v0);
    if (i0 + 2 < TOT) scanned[i0 + 2] = (unsigned int)(pre + v0 + v1);
    if (i0 + 3 < TOT) scanned[i0 + 3] = (unsigned int)(pre + v0 + v1 + v2);
}

// Pass C: scatter edges into bucket-grouped semi[] via LDS cursors.
// semi[pos] = {row | (col&63)<<17, wbits} (int2, row < 2^17).
__global__ __launch_bounds__(512)
void scatterC_kernel(const int* __restrict__ row, const int* __restrict__ col,
                     const float* __restrict__ w,
                     const unsigned int* __restrict__ scanned,
                     int2* __restrict__ semi, int E, int NB, int chunk) {
    __shared__ unsigned int cur[MAXNB];
    int t = blockIdx.x;
    for (int b = threadIdx.x; b < NB; b += 512)
        cur[b] = scanned[(size_t)b * TB + t];
    __syncthreads();
    int s = t * chunk, e = min(s + chunk, E);
    for (int i = s + threadIdx.x; i < e; i += 512) {
        int c = col[i];
        unsigned int pos = atomicAdd(&cur[(unsigned int)c >> BKT_SHIFT], 1u);
        semi[pos] = make_int2(row[i] | ((c & 63) << 17), __float_as_int(w[i]));
    }
}

// Pass D1: one block per bucket (64 nodes). Counts + weighted degree ->
// offs, dinv. Reads semi once; all atomics LDS.
__global__ __launch_bounds__(256)
void fineD1_kernel(const int2* __restrict__ semi, const unsigned int* __restrict__ scanned,
                   int* __restrict__ offs, float* __restrict__ dinv,
                   int E, int N, int NB) {
    __shared__ unsigned int cnt[64], wsum[64];
    int b = blockIdx.x, tid = threadIdx.x;
    int s = (int)scanned[(size_t)b * TB];
    int e = (b + 1 < NB) ? (int)scanned[(size_t)(b + 1) * TB] : E;
    if (tid < 64) { cnt[tid] = 0u; wsum[tid] = 0u; }
    __syncthreads();
    for (int i = s + tid; i < e; i += 256) {
        int2 v = semi[i];
        int c6 = (v.x >> 17) & 63;
        atomicAdd(&cnt[c6], 1u);
        atomicAdd(&wsum[c6], (unsigned int)llrintf(__int_as_float(v.y) * FXSCALE));
    }
    __syncthreads();
    if (tid < 64) {
        int v = (int)cnt[tid];
        int incl = v;
#pragma unroll
        for (int off = 1; off < 64; off <<= 1) {
            int u = __shfl_up(incl, off, 64);
            if (tid >= off) incl += u;
        }
        int node = (b << BKT_SHIFT) + tid;
        if (node < N) {
            offs[node] = s + (incl - v);       // exclusive within bucket + base
            float deg = (float)wsum[tid] * (1.0f / FXSCALE);
            dinv[node] = rsqrtf(deg + 1.0f);
        }
    }
    if (b == NB - 1 && tid == 0) offs[N] = E;
}

// Pass D2: scatter with NORM FUSED. Cursors seeded from offs (global
// positions); reads semi once; dinv[col] preloaded to LDS, dinv[row]
// random (L2-hot, 400KB).
__global__ __launch_bounds__(256)
void fineD2_kernel(const int2* __restrict__ semi, const unsigned int* __restrict__ scanned,
                   const int* __restrict__ offs, const float* __restrict__ dinv,
                   int2* __restrict__ perm, int E, int N, int NB) {
    __shared__ unsigned int cur[64];
    __shared__ float dloc[64];
    int b = blockIdx.x, tid = threadIdx.x;
    int s = (int)scanned[(size_t)b * TB];
    int e = (b + 1 < NB) ? (int)scanned[(size_t)(b + 1) * TB] : E;
    if (tid < 64) {
        int node = (b << BKT_SHIFT) + tid;
        cur[tid] = (node < N) ? (unsigned int)offs[node] : 0u;
        dloc[tid] = (node < N) ? dinv[node] : 0.f;
    }
    __syncthreads();
    for (int i = s + tid; i < e; i += 256) {
        int2 v = semi[i];
        int c6 = (v.x >> 17) & 63;
        int r = v.x & 0x1FFFF;
        unsigned int p = atomicAdd(&cur[c6], 1u);
        float nm = dinv[r] * __int_as_float(v.y) * dloc[c6];
        perm[p] = make_int2(r, __float_as_int(nm));
    }
}

// W3 -> bf16 packed for MFMA B-fragments: W3p[(c*128+col)*32 + kk] =
// bf16(W3[c*32+kk][col]), zero for k >= 80. 3 chunks of K=32.
__global__ void w3prep_kernel(const float* __restrict__ W3, ushort* __restrict__ W3p) {
    int i = blockIdx.x * 256 + threadIdx.x;
    if (i >= 3 * 128 * 32) return;
    int kk = i & 31, c = i >> 12, colv = (i >> 5) & 127;
    int k = c * 32 + kk;
    float v = (k < 80) ? W3[k * 128 + colv] : 0.f;
    W3p[i] = f2bf(v);
}

// Fused conv (conv1/conv2): phase1 = R11 gather into LDS agg (rows padded to
// K+4 floats vs phase-2 bank conflicts); sync; phase2 = gemm from LDS, relu,
// bf16 out. NPB=32 -> exactly ONE gather round per thread (no round convoy).
template<int K, int FOUT, int NPB, int BLK>
__global__ __launch_bounds__(BLK)
void fused_conv_kernel(const int* __restrict__ offs, const int2* __restrict__ perm,
                       const ushort* __restrict__ H, const float* __restrict__ dinv,
                       const float* __restrict__ W, const float* __restrict__ bias,
                       ushort* __restrict__ out, int N) {
    constexpr int TPN = K / 4;
    constexpr int TPQ = FOUT / 4;
    constexpr int NPT = (NPB * TPQ) / BLK;   // nodes per phase-2 thread
    constexpr int KP = K + 4;              // padded agg row (floats)
    static_assert((NPB * TPN) % BLK == 0, "phase1 tiling");
    static_assert(NPT >= 1 && (NPB % NPT) == 0, "phase2 nodes");
    static_assert((NPB / NPT) * TPQ == BLK, "phase2 tiling");
    __shared__ float wsm[K * FOUT];
    __shared__ float aggs[NPB * KP];
    for (int i = threadIdx.x; i < K * FOUT; i += BLK) wsm[i] = W[i];

    // ---- phase 1: gather into LDS ----
#pragma unroll
    for (int p0 = 0; p0 < NPB * TPN; p0 += BLK) {
        int p = p0 + threadIdx.x;
        int nl = p / TPN, q = p % TPN;
        int node = blockIdx.x * NPB + nl;
        float4 a0 = make_float4(0.f, 0.f, 0.f, 0.f);
        float4 a1 = make_float4(0.f, 0.f, 0.f, 0.f);
        if (node < N) {
            int s = offs[node], e = offs[node + 1];
            int j = s;
            for (; j + 4 <= e; j += 4) {
                int2 p0e = perm[j + 0], p1e = perm[j + 1];
                int2 p2e = perm[j + 2], p3e = perm[j + 3];
                ushort4 u0 = *(const ushort4*)(H + (long)p0e.x * K + q * 4);
                ushort4 u1 = *(const ushort4*)(H + (long)p1e.x * K + q * 4);
                ushort4 u2 = *(const ushort4*)(H + (long)p2e.x * K + q * 4);
                ushort4 u3 = *(const ushort4*)(H + (long)p3e.x * K + q * 4);
                ACC4(a0, u0, __int_as_float(p0e.y));
                ACC4(a1, u1, __int_as_float(p1e.y));
                ACC4(a0, u2, __int_as_float(p2e.y));
                ACC4(a1, u3, __int_as_float(p3e.y));
            }
            for (; j < e; ++j) {
                int2 pe = perm[j];
                ushort4 u = *(const ushort4*)(H + (long)pe.x * K + q * 4);
                ACC4(a0, u, __int_as_float(pe.y));
            }
            float di = dinv[node], d2 = di * di;
            ushort4 su = *(const ushort4*)(H + (long)node * K + q * 4);
            ACC4(a0, su, d2);
        }
        a0.x += a1.x; a0.y += a1.y; a0.z += a1.z; a0.w += a1.w;
        *(float4*)&aggs[nl * KP + q * 4] = a0;
    }
    __syncthreads();

    // ---- phase 2: gemm from LDS ----
    int q = threadIdx.x % TPQ, pg = threadIdx.x / TPQ;
    long nbase = (long)blockIdx.x * NPB + (long)pg * NPT;
    float4 acc[NPT];
#pragma unroll
    for (int t = 0; t < NPT; ++t) acc[t] = make_float4(0.f, 0.f, 0.f, 0.f);
    const float* wq = wsm + q * 4;
#pragma unroll 4
    for (int i = 0; i < K / 4; ++i) {
        float4 xv[NPT];
#pragma unroll
        for (int t = 0; t < NPT; ++t)
            xv[t] = *(const float4*)&aggs[(pg * NPT + t) * KP + i * 4];
#pragma unroll
        for (int j = 0; j < 4; ++j) {
            float4 wv = *(const float4*)(wq + (i * 4 + j) * FOUT);
#pragma unroll
            for (int t = 0; t < NPT; ++t) {
                float v = ((const float*)&xv[t])[j];
                acc[t].x += v * wv.x; acc[t].y += v * wv.y;
                acc[t].z += v * wv.z; acc[t].w += v * wv.w;
            }
        }
    }
    float4 bv = *(const float4*)(bias + q * 4);
#pragma unroll
    for (int t = 0; t < NPT; ++t) {
        long n = nbase + t;
        if (n < N) {
            float ox = fmaxf(acc[t].x + bv.x, 0.f);
            float oy = fmaxf(acc[t].y + bv.y, 0.f);
            float oz = fmaxf(acc[t].z + bv.z, 0.f);
            float ow = fmaxf(acc[t].w + bv.w, 0.f);
            *(ushort4*)(out + n * FOUT + q * 4) =
                make_ushort4(f2bf(ox), f2bf(oy), f2bf(oz), f2bf(ow));
        }
    }
}

// conv3 gather (R11 body): thread = (node, 4 feats of 80); OUTPUT bf16 into
// padded rows (stride KS=96). Pads k=80..95 zeroed INLINE by q<4 threads
// (replaces the 19.2MB aggB memset). Tail rows >= N stay garbage -> discarded
// at the node<N pool guard in conv3_mfma (MFMA rows are independent).
template<int F, int KS>
__global__ void gather_bf16_kernel(const int* __restrict__ offs,
                                   const int2* __restrict__ perm,
                                   const ushort* __restrict__ H,
                                   const float* __restrict__ dinv,
                                   ushort* __restrict__ agg, int N) {
    constexpr int TPN = F / 4;
    int idx = blockIdx.x * blockDim.x + threadIdx.x;
    int node = idx / TPN, q = idx % TPN;
    if (node >= N) return;
    int s = offs[node], e = offs[node + 1];
    float4 a0 = make_float4(0.f, 0.f, 0.f, 0.f);
    float4 a1 = make_float4(0.f, 0.f, 0.f, 0.f);
    int j = s;
    for (; j + 4 <= e; j += 4) {
        int2 p0 = perm[j + 0], p1 = perm[j + 1], p2 = perm[j + 2], p3 = perm[j + 3];
        ushort4 u0 = *(const ushort4*)(H + (long)p0.x * F + q * 4);
        ushort4 u1 = *(const ushort4*)(H + (long)p1.x * F + q * 4);
        ushort4 u2 = *(const ushort4*)(H + (long)p2.x * F + q * 4);
        ushort4 u3 = *(const ushort4*)(H + (long)p3.x * F + q * 4);
        ACC4(a0, u0, __int_as_float(p0.y));
        ACC4(a1, u1, __int_as_float(p1.y));
        ACC4(a0, u2, __int_as_float(p2.y));
        ACC4(a1, u3, __int_as_float(p3.y));
    }
    for (; j < e; ++j) {
        int2 p = perm[j];
        ushort4 u = *(const ushort4*)(H + (long)p.x * F + q * 4);
        ACC4(a0, u, __int_as_float(p.y));
    }
    float di = dinv[node], d2 = di * di;
    ushort4 su = *(const ushort4*)(H + (long)node * F + q * 4);
    ACC4(a0, su, d2);
    a0.x += a1.x; a0.y += a1.y; a0.z += a1.z; a0.w += a1.w;
    *(ushort4*)(agg + (long)node * KS + q * 4) =
        make_ushort4(f2bf(a0.x), f2bf(a0.y), f2bf(a0.z), f2bf(a0.w));
    if (q < 4)   // zero pad slots 80..95 (4 x ushort4)
        *(ushort4*)(agg + (long)node * KS + F + q * 4) = make_ushort4(0, 0, 0, 0);
}

// conv3 MFMA gemm + pool: uniform coalesced copy of NPB=64 agg rows (bf16,
// stride KS=96) into LDS -> 24x v_mfma_f32_16x16x32_bf16 per wave (R24
// layout, HW-verified) -> relu + hierarchical max-pool.
// Copy = 12288B = 768 uint4 = 3/thread.
template<int FOUT, int NPB, int BLK>   // 128, 64, 256
__global__ __launch_bounds__(BLK)
void conv3_mfma_pool_kernel(const ushort* __restrict__ aggB,
                            const ushort* __restrict__ W3p,
                            const float* __restrict__ bias,
                            const int* __restrict__ batch,
                            unsigned int* __restrict__ g, int N) {
    constexpr int KS = 96;
    static_assert(NPB == 64 && BLK == 256 && FOUT == 128, "mfma tiling");
    __shared__ ushort aggs[NPB * KS];      // 12KB
    __shared__ unsigned int gma[2 * FOUT];
    __shared__ int sb[NPB];
    __shared__ int gfirst;
    int bb = blockIdx.x * NPB;
    int tid = (int)threadIdx.x;
    if (tid == 0) gfirst = batch[min(bb, N - 1)];
    if (tid < NPB) sb[tid] = batch[min(bb + tid, N - 1)];
    for (int i = tid; i < 2 * FOUT; i += BLK) gma[i] = 0u;
    // uniform copy: 64*96 ushorts = 12288B = 768 uint4 (16B), 3 per thread
    {
        const uint4* src = (const uint4*)(aggB + (size_t)bb * KS);
        uint4* dst = (uint4*)aggs;
#pragma unroll
        for (int i = 0; i < 3; ++i) dst[tid + i * BLK] = src[tid + i * BLK];
    }
    __syncthreads();

    // ---- MFMA gemm + pool ----
    int lane = tid & 63, w = tid >> 6;     // 4 waves, 16 rows each
    int la = lane & 15, kg = lane >> 4;
    f32x4 acc[8];
#pragma unroll
    for (int t = 0; t < 8; ++t) acc[t] = (f32x4){0.f, 0.f, 0.f, 0.f};
#pragma unroll
    for (int c = 0; c < 3; ++c) {
        bf16x8 a = *(const bf16x8*)&aggs[(w * 16 + la) * KS + c * 32 + kg * 8];
        const ushort* bp = W3p + (size_t)c * 4096 + la * 32 + kg * 8;
#pragma unroll
        for (int t = 0; t < 8; ++t) {
            bf16x8 b = *(const bf16x8*)(bp + t * 512);
            acc[t] = __builtin_amdgcn_mfma_f32_16x16x32_bf16(a, b, acc[t], 0, 0, 0);
        }
    }
    // C/D: col = t*16 + (lane&15), row = w*16 + (lane>>4)*4 + r
    int rowg = w * 16 + kg * 4;
#pragma unroll
    for (int t = 0; t < 8; ++t) {
        int colv = t * 16 + la;
        float bvv = bias[colv];
#pragma unroll
        for (int r = 0; r < 4; ++r) {
            int nl = rowg + r;
            long node = (long)bb + nl;
            if (node < N) {
                float v = fmaxf(acc[t][r] + bvv, 0.f);
                unsigned int uv = __float_as_uint(v);
                int bn = sb[nl];
                int rel = bn - gfirst;
                if (rel < 2) atomicMax(&gma[rel * FOUT + colv], uv);
                else atomicMax(&g[(long)bn * FOUT + colv], uv);
            }
        }
    }
    __syncthreads();
    for (int i = tid; i < 2 * FOUT; i += BLK) {
        unsigned int v = gma[i];
        if (v) atomicMax(&g[(long)(gfirst + i / FOUT) * FOUT + (i % FOUT)], v);
    }
}

// one block per graph: relu(g@Wfc1+bfc1) @ Wfc2 + bfc2 -> softmax
__global__ void fc_kernel(const float* __restrict__ g, const float* __restrict__ Wfc1,
                          const float* __restrict__ bfc1, const float* __restrict__ Wfc2,
                          const float* __restrict__ bfc2, float* __restrict__ out) {
    __shared__ float gs[128];
    __shared__ float red0[256], red1[256];
    int b = blockIdx.x, tid = threadIdx.x;
    if (tid < 128) gs[tid] = g[b * 128 + tid];
    __syncthreads();
    float h0 = bfc1[tid], h1 = bfc1[tid + 256];
    for (int k = 0; k < 128; ++k) {
        float gv = gs[k];
        h0 += gv * Wfc1[k * 512 + tid];
        h1 += gv * Wfc1[k * 512 + tid + 256];
    }
    h0 = fmaxf(h0, 0.f); h1 = fmaxf(h1, 0.f);
    red0[tid] = h0 * Wfc2[tid * 2 + 0] + h1 * Wfc2[(tid + 256) * 2 + 0];
    red1[tid] = h0 * Wfc2[tid * 2 + 1] + h1 * Wfc2[(tid + 256) * 2 + 1];
    __syncthreads();
    for (int s = 128; s > 0; s >>= 1) {
        if (tid < s) { red0[tid] += red0[tid + s]; red1[tid] += red1[tid + s]; }
        __syncthreads();
    }
    if (tid == 0) {
        float L0 = red0[0] + bfc2[0], L1 = red1[0] + bfc2[1];
        float m = fmaxf(L0, L1);
        float e0 = expf(L0 - m), e1 = expf(L1 - m);
        float inv = 1.f / (e0 + e1);
        out[b * 2 + 0] = e0 * inv;
        out[b * 2 + 1] = e1 * inv;
    }
}

extern "C" void kernel_launch(void* const* d_in, const int* in_sizes, int n_in,
                              void* d_out, int out_size, void* d_ws, size_t ws_size,
                              hipStream_t stream) {
    const float* x     = (const float*)d_in[0];
    const int*   ei    = (const int*)d_in[1];
    const float* ew    = (const float*)d_in[2];
    const int*   batch = (const int*)d_in[3];
    const float* W1    = (const float*)d_in[4];
    const float* b1    = (const float*)d_in[5];
    const float* W2    = (const float*)d_in[6];
    const float* b2    = (const float*)d_in[7];
    const float* W3    = (const float*)d_in[8];
    const float* b3    = (const float*)d_in[9];
    const float* Wfc1  = (const float*)d_in[10];
    const float* bfc1  = (const float*)d_in[11];
    const float* Wfc2  = (const float*)d_in[12];
    const float* bfc2  = (const float*)d_in[13];

    const int N = in_sizes[3];      // 100000
    const int E = in_sizes[2];      // 1600000
    const int* row = ei;
    const int* col = ei + E;

    char* ws = (char*)d_ws;
    float* dinv   = (float*)ws;              ws += align256((size_t)N * 4);
    int*   offs   = (int*)ws;                ws += align256((size_t)(N + 1) * 4);
    int*   bsums  = (int*)ws;                ws += align256((size_t)1024 * 4);
    int2*  perm   = (int2*)ws;               ws += align256((size_t)E * 8);
    float* bufA   = (float*)ws;              ws += align256((size_t)N * 128 * 4);  // build transients / aggB
    ushort* bufH1 = (ushort*)ws;             ws += align256((size_t)N * 40 * 2);   // H1 bf16
    ushort* bufH2 = (ushort*)ws;             ws += align256((size_t)N * 80 * 2);   // H2 bf16
    ushort* xbf   = (ushort*)ws;             ws += align256((size_t)N * 40 * 2);   // x bf16
    float* g      = (float*)ws;              ws += align256((size_t)512 * 128 * 4);
    ushort* W3p   = (ushort*)ws;             ws += align256((size_t)3 * 128 * 32 * 2);

    const int NB   = cdiv(N, 64);            // 1563 buckets (<= MAXNB)
    const int TOT  = NB * TB;                // (bucket, tile) cells = 400128
    const int chunkE = cdiv(E, TB);          // edges per tile = 6250
    const int nScanH = cdiv(TOT, SCHUNK);    // 391 (<= 1024)

    // transients aliased into bufA (51.2MB; all dead before convs):
    // semi int2 (12.8MB) | gHist u32[TOT] (1.6MB) | scanned u32[TOT] (1.6MB)
    // later: aggB ushort[N64*96] (19.2MB) for conv3 split
    int2* semi = (int2*)bufA;
    unsigned int* gHist =
        (unsigned int*)((char*)bufA + align256((size_t)E * 8));
    unsigned int* scanned =
        (unsigned int*)((char*)gHist + align256((size_t)TOT * 4));
    ushort* aggB = (ushort*)bufA;

    const int B = 256;

    // --- atomic-free CSR build (normE fused into D2) ---
    histA_kernel<<<TB, 512, 0, stream>>>(col, gHist, E, NB, chunkE,
                                         x, xbf, (long)N * 10);
    scanAH_kernel<<<nScanH, B, 0, stream>>>(gHist, bsums, TOT, NB);
    scanB_kernel<<<1, 1024, 0, stream>>>(bsums, offs, nScanH, N);
    scanCH_kernel<<<nScanH, B, 0, stream>>>(gHist, bsums, scanned, TOT, NB);
    scatterC_kernel<<<TB, 512, 0, stream>>>(row, col, ew, scanned, semi, E, NB, chunkE);
    fineD1_kernel<<<NB, 256, 0, stream>>>(semi, scanned, offs, dinv, E, N, NB);
    fineD2_kernel<<<NB, 256, 0, stream>>>(semi, scanned, offs, dinv, perm, E, N, NB);
    w3prep_kernel<<<48, 256, 0, stream>>>(W3, W3p);

    // --- conv1 fused (1 gather round): H1 = relu((A*x)@W1 + b1) -> bufH1 ---
    fused_conv_kernel<40, 40, 32, 320><<<cdiv(N, 32), 320, 0, stream>>>(
        offs, perm, xbf, dinv, W1, b1, bufH1, N);

    // --- conv2 fused (1 gather round): H2 = relu((A*H1)@W2 + b2) -> bufH2 ---
    fused_conv_kernel<40, 80, 32, 320><<<cdiv(N, 32), 320, 0, stream>>>(
        offs, perm, bufH1, dinv, W2, b2, bufH2, N);

    // --- conv3 split: gather bf16 agg (inline pad-zero) -> MFMA gemm + pool ---
    gather_bf16_kernel<80, 96><<<cdiv((long)N * 20, B), B, 0, stream>>>(
        offs, perm, bufH2, dinv, aggB, N);
    hipMemsetAsync(g, 0, (size_t)512 * 128 * 4, stream);
    conv3_mfma_pool_kernel<128, 64, 256><<<NB, 256, 0, stream>>>(
        aggB, W3p, b3, batch, (unsigned int*)g, N);

    // --- MLP + softmax ---
    fc_kernel<<<512, 256, 0, stream>>>(g, Wfc1, bfc1, Wfc2, bfc2, (float*)d_out);
}